// Round 13
// baseline (671.824 us; speedup 1.0000x reference)
//
#include <hip/hip_runtime.h>
#include <stdint.h>

typedef __bf16 bf16_t;
typedef __bf16 bf16x8 __attribute__((ext_vector_type(8)));
typedef __bf16 bf16x4 __attribute__((ext_vector_type(4)));
typedef float  f32x4  __attribute__((ext_vector_type(4)));

constexpr int cBS = 64, cP = 512, cD = 1024, cDWM = 1024, cH = 16, cHD = 64, cW = 128;
constexpr int cVTP = 672;           // padded p-extent of Vt (sp = p + 128, max used 656)
constexpr int cM = cBS * cP;        // 32768
constexpr float cSCALE = 0.125f;    // 1/sqrt(64)

__device__ __forceinline__ void gld_lds16(const void* g, void* l) {
#if __has_builtin(__builtin_amdgcn_global_load_lds)
  __builtin_amdgcn_global_load_lds(
      (__attribute__((address_space(1))) void*)g,
      (__attribute__((address_space(3))) void*)l, 16, 0, 0);
#else
  *(bf16x8*)l = *(const bf16x8*)g;
#endif
}

// ---------------------------------------------------------------------------
// fp32 -> bf16 conversion of X: 8 elems/thread, 16-B stores, grid-stride.
__global__ void cvt_x_k(const float* __restrict__ X, bf16_t* __restrict__ Y, int n) {
  const int nthreads = gridDim.x * blockDim.x;
  const int n8 = n >> 3;
  for (int i = blockIdx.x * blockDim.x + threadIdx.x; i < n8; i += nthreads) {
    const float4 a = *(const float4*)(X + (size_t)i * 8);
    const float4 b = *(const float4*)(X + (size_t)i * 8 + 4);
    bf16x8 o;
    o[0] = (bf16_t)a.x; o[1] = (bf16_t)a.y; o[2] = (bf16_t)a.z; o[3] = (bf16_t)a.w;
    o[4] = (bf16_t)b.x; o[5] = (bf16_t)b.y; o[6] = (bf16_t)b.z; o[7] = (bf16_t)b.w;
    *(bf16x8*)(Y + (size_t)i * 8) = o;
  }
}

// transpose + convert the four 1024x1024 weights: W[k][n] fp32 -> Wt[n][k] bf16
__global__ void cvt_wt_k(const float* __restrict__ W0, const float* __restrict__ W1,
                         const float* __restrict__ W2, const float* __restrict__ W3,
                         bf16_t* __restrict__ T0, bf16_t* __restrict__ T1,
                         bf16_t* __restrict__ T2, bf16_t* __restrict__ T3) {
  __shared__ float tile[32][33];
  const float* Wsrc; bf16_t* Tdst;
  switch (blockIdx.z) {
    case 0: Wsrc = W0; Tdst = T0; break;
    case 1: Wsrc = W1; Tdst = T1; break;
    case 2: Wsrc = W2; Tdst = T2; break;
    default: Wsrc = W3; Tdst = T3; break;
  }
  const int n0 = blockIdx.x * 32, k0 = blockIdx.y * 32;
  const int c = threadIdx.x & 31, r8 = threadIdx.x >> 5;
#pragma unroll
  for (int q = 0; q < 4; ++q) {
    int row = r8 + q * 8;
    tile[row][c] = Wsrc[(size_t)(k0 + row) * 1024 + n0 + c];
  }
  __syncthreads();
#pragma unroll
  for (int q = 0; q < 4; ++q) {
    int row = r8 + q * 8;
    Tdst[(size_t)(n0 + row) * 1024 + k0 + c] = (bf16_t)tile[c][row];
  }
}

// r[b][t] = index of last reset at-or-before t (0 if none): parallel max-scan
__global__ void resets2_k(const int* __restrict__ mask, int* __restrict__ r) {
  __shared__ int sm[cP];
  const int b = blockIdx.x, t = threadIdx.x;
  sm[t] = mask[b * cP + t] ? t : 0;
  __syncthreads();
#pragma unroll
  for (int d = 1; d < cP; d <<= 1) {
    int u = (t >= d) ? sm[t - d] : 0;
    __syncthreads();
    if (u > sm[t]) sm[t] = u;
    __syncthreads();
  }
  r[b * cP + t] = sm[t];
}

// ---------------------------------------------------------------------------
// 256x256 GEMM core, r13 = r1's verified 8-phase counted-vmcnt schedule
// + r9's nb-slowest XCD mapping (never previously combined — r1's null was
// measured in the L2-thrash regime; r9 removed that wall, so the phase
// interleave is now the candidate lever for the measured LDS+MFMA serial-sum
// at MfmaUtil 44%).
//   Per K-tile 4 phases: q0{12 ds_read | stage h+5 | barrier | lgkm0 | 16 MFMA}
//   q1{4 ds_read | stage h+6 | ...} q2{8 ds_read | stage h+7 | ...}
//   q3{stage h+8 | 16 MFMA | vmcnt(2) counted (never 0 mid-loop)}.
#define MFMA_B16(a, b, c) c = __builtin_amdgcn_mfma_f32_16x16x32_bf16(a, b, c, 0, 0, 0)

template <int NBLK>
__device__ __forceinline__ void gemm256_core(const bf16_t* __restrict__ A,
                                             const bf16_t* __restrict__ Bt,
                                             bf16_t* __restrict__ LDS,
                                             f32x4 (&acc)[8][4],
                                             int& m0_out, int& n0_out) {
  constexpr int K = 1024;
  bf16_t* Asf = LDS;            // [2][256*64]
  bf16_t* Bsf = LDS + 32768;    // [2][256*64]
  const int tid = threadIdx.x;
  const int wid = tid >> 6, ln = tid & 63;
  const int ln15 = ln & 15, g4 = ln >> 4;
  const int wr = wid >> 2, wc = wid & 3;

  // XCD swizzle, nb slowest: g = xcd + 8*(mloc + 16*nb)
  const int g = blockIdx.x;
  const int xcd = g & 7, s = g >> 3;
  const int nb = s >> 4, mloc = s & 15;
  const int m0 = (xcd * 16 + mloc) * 256, n0 = nb * 256;
  m0_out = m0; n0_out = n0;

  const bf16_t* Ag = A + (size_t)m0 * K;
  const bf16_t* Bg = Bt + (size_t)n0 * K;

  // Stage addressing: 8 (hh,l) slots; LDS dest linear (global_load_lds rule),
  // swizzle applied on the per-lane GLOBAL source group.
  const bf16_t* gsrc[8];
  bf16_t* ldst[8];
#pragma unroll
  for (int sl = 0; sl < 8; ++sl) {
    const int hh = sl >> 1, l = sl & 1;
    const int E = ((hh & 1) << 13) | (l << 12) | (tid << 3);
    const int row = E >> 6;
    const int cg = ((E >> 3) & 7) ^ (row & 7);
    gsrc[sl] = ((hh < 2) ? Ag : Bg) + (size_t)row * K + cg * 8;
    ldst[sl] = ((hh < 2) ? Asf : Bsf) + E;
  }
  // stage one half-tile ht: tile kt=ht>>2 (buf kt&1, k0=kt*64), half hh=ht&3
  auto stage_half = [&](int ht) {
    const int k0 = (ht >> 2) << 6, bo = ((ht >> 2) & 1) << 14;
    const int sl = (ht & 3) << 1;
    gld_lds16(gsrc[sl] + k0, ldst[sl] + bo);
    gld_lds16(gsrc[sl + 1] + k0, ldst[sl + 1] + bo);
  };

  const int rA = wr * 128 + ln15;
  const int rB = wc * 64 + ln15;
  const int sA0 = ((g4 ^ (ln15 & 7)) << 3), sA1 = (((4 | g4) ^ (ln15 & 7)) << 3);
  const bf16_t* pA = &Asf[rA * 64];
  const bf16_t* pB = &Bsf[rB * 64];

#pragma unroll
  for (int i = 0; i < 8; ++i)
#pragma unroll
    for (int j = 0; j < 4; ++j) acc[i][j] = {0.f, 0.f, 0.f, 0.f};

  // Prologue: tile0 fully + tile1 h0; drain to tile-0's 8 loads only.
#pragma unroll
  for (int ht = 0; ht < 5; ++ht) stage_half(ht);
  asm volatile("s_waitcnt vmcnt(2)" ::: "memory");
  __builtin_amdgcn_sched_barrier(0);
  __builtin_amdgcn_s_barrier();

  bf16x8 afr[8][2], bfr[4][2];

  for (int kt = 0; kt < 16; ++kt) {
    const int bo = (kt & 1) << 14, gp = kt << 2;
    const bf16_t* pAb = pA + bo;
    const bf16_t* pBb = pB + bo;

    // ---- q0: read A mh0 (8) + B n01 (4); MFMA (mh0 x n01) ----
#pragma unroll
    for (int i = 0; i < 4; ++i) {
      afr[i][0] = *(const bf16x8*)(pAb + i * 1024 + sA0);
      afr[i][1] = *(const bf16x8*)(pAb + i * 1024 + sA1);
    }
#pragma unroll
    for (int j = 0; j < 2; ++j) {
      bfr[j][0] = *(const bf16x8*)(pBb + j * 1024 + sA0);
      bfr[j][1] = *(const bf16x8*)(pBb + j * 1024 + sA1);
    }
    if (gp + 5 < 64) stage_half(gp + 5);
    asm volatile("s_waitcnt lgkmcnt(8)" ::: "memory");
    __builtin_amdgcn_s_barrier();
    asm volatile("s_waitcnt lgkmcnt(0)" ::: "memory");
    __builtin_amdgcn_sched_barrier(0);
    __builtin_amdgcn_s_setprio(1);
#pragma unroll
    for (int i = 0; i < 4; ++i)
#pragma unroll
      for (int j = 0; j < 2; ++j) {
        MFMA_B16(afr[i][0], bfr[j][0], acc[i][j]);
        MFMA_B16(afr[i][1], bfr[j][1], acc[i][j]);
      }
    __builtin_amdgcn_s_setprio(0);
    __builtin_amdgcn_s_barrier();

    // ---- q1: read B n23 (4); MFMA (mh0 x n23) ----
#pragma unroll
    for (int j = 2; j < 4; ++j) {
      bfr[j][0] = *(const bf16x8*)(pBb + j * 1024 + sA0);
      bfr[j][1] = *(const bf16x8*)(pBb + j * 1024 + sA1);
    }
    if (gp + 6 < 64) stage_half(gp + 6);
    __builtin_amdgcn_s_barrier();
    asm volatile("s_waitcnt lgkmcnt(0)" ::: "memory");
    __builtin_amdgcn_sched_barrier(0);
    __builtin_amdgcn_s_setprio(1);
#pragma unroll
    for (int i = 0; i < 4; ++i)
#pragma unroll
      for (int j = 2; j < 4; ++j) {
        MFMA_B16(afr[i][0], bfr[j][0], acc[i][j]);
        MFMA_B16(afr[i][1], bfr[j][1], acc[i][j]);
      }
    __builtin_amdgcn_s_setprio(0);
    __builtin_amdgcn_s_barrier();

    // ---- q2: read A mh1 (8); MFMA (mh1 x n23, reusing bfr[2..3]) ----
#pragma unroll
    for (int i = 4; i < 8; ++i) {
      afr[i][0] = *(const bf16x8*)(pAb + i * 1024 + sA0);
      afr[i][1] = *(const bf16x8*)(pAb + i * 1024 + sA1);
    }
    if (gp + 7 < 64) stage_half(gp + 7);
    __builtin_amdgcn_s_barrier();
    asm volatile("s_waitcnt lgkmcnt(0)" ::: "memory");
    __builtin_amdgcn_sched_barrier(0);
    __builtin_amdgcn_s_setprio(1);
#pragma unroll
    for (int i = 4; i < 8; ++i)
#pragma unroll
      for (int j = 2; j < 4; ++j) {
        MFMA_B16(afr[i][0], bfr[j][0], acc[i][j]);
        MFMA_B16(afr[i][1], bfr[j][1], acc[i][j]);
      }
    __builtin_amdgcn_s_setprio(0);
    __builtin_amdgcn_s_barrier();

    // ---- q3: no ds_read; MFMA (mh1 x n01, reusing bfr[0..1]); counted
    //      per-K-tile drain: tile kt+1 landed, tile kt+2 h0 may fly ----
    if (gp + 8 < 64) stage_half(gp + 8);
    __builtin_amdgcn_s_barrier();
    __builtin_amdgcn_s_setprio(1);
#pragma unroll
    for (int i = 4; i < 8; ++i)
#pragma unroll
      for (int j = 0; j < 2; ++j) {
        MFMA_B16(afr[i][0], bfr[j][0], acc[i][j]);
        MFMA_B16(afr[i][1], bfr[j][1], acc[i][j]);
      }
    __builtin_amdgcn_s_setprio(0);
    if (kt < 14) { asm volatile("s_waitcnt vmcnt(2)" ::: "memory"); }
    else         { asm volatile("s_waitcnt vmcnt(0)" ::: "memory"); }
    __builtin_amdgcn_sched_barrier(0);
    __builtin_amdgcn_s_barrier();
  }
}

// Q+K projection: C[32768][2048] = Xbf * Wqk^T (Wqt|Wkt contiguous).
// LDS-restaged epilogue (r11/r12: bf16x8 head-major stores).
__global__ __launch_bounds__(512, 2)
void gemm_qk_k(const bf16_t* __restrict__ A, const bf16_t* __restrict__ Wt,
               const float* __restrict__ bq, const float* __restrict__ bk,
               bf16_t* __restrict__ Qh, bf16_t* __restrict__ Kh) {
  __shared__ __align__(16) bf16_t LDS[65536];   // 128 KiB
  f32x4 acc[8][4];
  int m0, n0;
  gemm256_core<8>(A, Wt, LDS, acc, m0, n0);

  const int tid = threadIdx.x;
  const int wid = tid >> 6, ln = tid & 63;
  const int ln15 = ln & 15, g4 = ln >> 4;
  const int wr = wid >> 2, wc = wid & 3;

  const int seg = n0 >> 10;                      // block-uniform: 0=Q 1=K
  const float* bias = (seg == 0) ? bq : bk;
  bf16_t* QK = (seg == 0) ? Qh : Kh;
  const int b = m0 >> 9, pb0 = m0 & 511;         // block spans one batch

#pragma unroll
  for (int ci = 0; ci < 4; ++ci) {
#pragma unroll
    for (int i2 = 0; i2 < 2; ++i2) {
      const int i = ci * 2 + i2;
      const int cr = wr * 32 + i2 * 16 + g4 * 4;
#pragma unroll
      for (int j = 0; j < 4; ++j) {
        const int col = wc * 64 + j * 16 + ln15;
        const float bv = bias[(n0 & 1023) + col];
#pragma unroll
        for (int r = 0; r < 4; ++r)
          LDS[(cr + r) * 264 + col] = (bf16_t)(acc[i][j][r] + bv);
      }
    }
    __syncthreads();
#pragma unroll
    for (int k = 0; k < 4; ++k) {
      const int u = k * 512 + tid;
      const int row = u >> 5, cu = u & 31;
      const int wr2 = row >> 5, i2 = (row >> 4) & 1, r16 = row & 15;
      const int pb = pb0 + wr2 * 128 + (ci * 2 + i2) * 16 + r16;
      const int cl = (n0 & 1023) + cu * 8;
      const int h = cl >> 6, hd = cl & 63;
      const bf16x8 v = *(const bf16x8*)(&LDS[row * 264 + cu * 8]);
      *(bf16x8*)(QK + (((size_t)(b * cH + h)) * cP + pb) * cHD + hd) = v;
    }
    __syncthreads();
  }
}

// V projection: Vt transposed layout (bf16x4 stores along p).
__global__ __launch_bounds__(512, 2)
void gemm_v_k(const bf16_t* __restrict__ A, const bf16_t* __restrict__ Wt,
              const float* __restrict__ bias, bf16_t* __restrict__ Vt) {
  __shared__ __align__(16) bf16_t LDS[65536];
  f32x4 acc[8][4];
  int m0, n0;
  gemm256_core<4>(A, Wt, LDS, acc, m0, n0);

  const int tid = threadIdx.x;
  const int wid = tid >> 6, ln = tid & 63;
  const int ln15 = ln & 15, g4 = ln >> 4;
  const int wr = wid >> 2, wc = wid & 3;

#pragma unroll
  for (int i = 0; i < 8; ++i) {
    const int rbase = m0 + wr * 128 + i * 16 + g4 * 4;
    const int b = rbase >> 9, pb = rbase & 511;
#pragma unroll
    for (int j = 0; j < 4; ++j) {
      const int cl = n0 + wc * 64 + j * 16 + ln15;   // [0,1024)
      const int h = cl >> 6, hd = cl & 63;
      const float bv = bias[cl];
      bf16x4 pk;
#pragma unroll
      for (int r = 0; r < 4; ++r) pk[r] = (bf16_t)(acc[i][j][r] + bv);
      *(bf16x4*)(Vt + ((size_t)((b * cH + h) * cHD + hd)) * cVTP + 128 + pb) = pk;
    }
  }
}

// Output projection: C[32768][1024] fp32 = Ob * Wot^T + bo (LDS-restaged).
__global__ __launch_bounds__(512, 2)
void gemm_bt3_k(const bf16_t* __restrict__ A, const bf16_t* __restrict__ Bt,
                const float* __restrict__ bias, float* __restrict__ C) {
  __shared__ __align__(16) bf16_t LDS[65536];
  f32x4 acc[8][4];
  int m0, n0;
  gemm256_core<4>(A, Bt, LDS, acc, m0, n0);

  const int tid = threadIdx.x;
  const int wid = tid >> 6, ln = tid & 63;
  const int ln15 = ln & 15, g4 = ln >> 4;
  const int wr = wid >> 2, wc = wid & 3;
  float* ldsf = (float*)LDS;                     // [64][264] fp32 staging

#pragma unroll
  for (int ci = 0; ci < 4; ++ci) {
#pragma unroll
    for (int i2 = 0; i2 < 2; ++i2) {
      const int i = ci * 2 + i2;
      const int cr = wr * 32 + i2 * 16 + g4 * 4;
#pragma unroll
      for (int j = 0; j < 4; ++j) {
        const int col = wc * 64 + j * 16 + ln15;
        const float bv = bias[n0 + col];
#pragma unroll
        for (int r = 0; r < 4; ++r)
          ldsf[(cr + r) * 264 + col] = acc[i][j][r] + bv;
      }
    }
    __syncthreads();
#pragma unroll
    for (int k = 0; k < 8; ++k) {
      const int u = k * 512 + tid;
      const int row = u >> 6, cu = u & 63;
      const int wr2 = row >> 5, i2 = (row >> 4) & 1, r16 = row & 15;
      const int grow = m0 + wr2 * 128 + (ci * 2 + i2) * 16 + r16;
      const f32x4 v = *(const f32x4*)(&ldsf[row * 264 + cu * 4]);
      *(f32x4*)(C + (size_t)grow * cD + n0 + cu * 4) = v;
    }
    __syncthreads();
  }
}

// ---------------------------------------------------------------------------
// Windowed attention v8 (r12: K window staged once; Q/rr/V prefetched into
// registers before each sub's QK^T; PV from prefetched V regs).
__global__ __launch_bounds__(256, 2)
void attn8_k(const bf16_t* __restrict__ Q, const bf16_t* __restrict__ Kv,
             const bf16_t* __restrict__ Vt, const int* __restrict__ rr,
             bf16_t* __restrict__ O) {
  __shared__ __align__(16) bf16_t Ks[256 * 72];
  __shared__ __align__(16) bf16_t Pl[4][16][168];
  const int tid = threadIdx.x;
  const int wv = tid >> 6, ln = tid & 63, ln15 = ln & 15, g4 = ln >> 4;
  const int h = blockIdx.x, b = blockIdx.y, tc = blockIdx.z;
  bf16_t(*Pw)[168] = Pl[wv];
  const bf16_t* vb = Vt + ((size_t)(b * cH + h)) * cHD * cVTP;
  const bf16_t* qb = Q + ((size_t)(b * cH + h)) * cP * cHD;
  const bf16_t* kb = Kv + ((size_t)(b * cH + h)) * cP * cHD;

  const int kbase = tc * 128 - 128;
#pragma unroll
  for (int p = 0; p < 8; ++p) {
    const int slot = p * 256 + tid;
    const int row = slot >> 3, cg = slot & 7;
    const int s = kbase + row;
    bf16x8 v;
    if ((unsigned)s < (unsigned)cP) {
      v = *(const bf16x8*)(kb + (size_t)s * cHD + cg * 8);
    } else {
#pragma unroll
      for (int z = 0; z < 8; ++z) v[z] = (bf16_t)0.f;
    }
    *(bf16x8*)(Ks + row * 72 + cg * 8) = v;
  }

  const int t00 = tc * 128 + wv * 16;
  const bf16_t* qp0 = qb + (size_t)(t00 + ln15) * cHD + g4 * 8;
  const bf16x8 qa00 = *(const bf16x8*)qp0;
  const bf16x8 qa01 = *(const bf16x8*)(qp0 + 32);
  const bf16_t* qp1 = qp0 + 64 * cHD;
  const bf16x8 qa10 = *(const bf16x8*)qp1;
  const bf16x8 qa11 = *(const bf16x8*)(qp1 + 32);
  const int4 rva = *(const int4*)(rr + b * cP + t00 + g4 * 4);
  const int4 rvb = *(const int4*)(rr + b * cP + t00 + 64 + g4 * 4);

  __syncthreads();

#pragma unroll
  for (int sub = 0; sub < 2; ++sub) {
    const int t0 = t00 + sub * 64;
    const int sbase = t0 - 128;
    const bf16x8 qa0 = sub ? qa10 : qa00;
    const bf16x8 qa1 = sub ? qa11 : qa01;
    const int4 rvv = sub ? rvb : rva;
    const int rv[4] = {rvv.x, rvv.y, rvv.z, rvv.w};

    bf16x8 vf[4][5];
#pragma unroll
    for (int j = 0; j < 4; ++j) {
      const bf16_t* vrow = vb + (size_t)(j * 16 + ln15) * cVTP + t0 + g4 * 8;
#pragma unroll
      for (int c2 = 0; c2 < 5; ++c2) vf[j][c2] = *(const bf16x8*)(vrow + c2 * 32);
    }

    const bf16_t* kls = Ks + (sub * 64 + wv * 16 + ln15) * 72 + g4 * 8;
    f32x4 lg[9];
#pragma unroll
    for (int c = 0; c < 9; ++c) {
      const bf16_t* kp = kls + c * (16 * 72);
      const bf16x8 k0v = *(const bf16x8*)kp;
      const bf16x8 k1v = *(const bf16x8*)(kp + 32);
      f32x4 a = {0.f, 0.f, 0.f, 0.f};
      a = __builtin_amdgcn_mfma_f32_16x16x32_bf16(qa0, k0v, a, 0, 0, 0);
      a = __builtin_amdgcn_mfma_f32_16x16x32_bf16(qa1, k1v, a, 0, 0, 0);
      lg[c] = a;
    }

    float mx[4] = {-1e30f, -1e30f, -1e30f, -1e30f};
#pragma unroll
    for (int c = 0; c < 9; ++c)
#pragma unroll
      for (int r = 0; r < 4; ++r) {
        const int s = sbase + c * 16 + ln15;
        const int t = t0 + g4 * 4 + r;
        const bool ok = (s >= rv[r]) && (s <= t) && (t - s < cW);
        const float l = ok ? lg[c][r] * cSCALE : -1e30f;
        lg[c][r] = l;
        mx[r] = fmaxf(mx[r], l);
      }
#pragma unroll
    for (int r = 0; r < 4; ++r) {
      mx[r] = fmaxf(mx[r], __shfl_xor(mx[r], 1));
      mx[r] = fmaxf(mx[r], __shfl_xor(mx[r], 2));
      mx[r] = fmaxf(mx[r], __shfl_xor(mx[r], 4));
      mx[r] = fmaxf(mx[r], __shfl_xor(mx[r], 8));
    }
    float sm[4] = {0.f, 0.f, 0.f, 0.f};
#pragma unroll
    for (int c = 0; c < 9; ++c)
#pragma unroll
      for (int r = 0; r < 4; ++r) {
        const float e = __expf(lg[c][r] - mx[r]);
        lg[c][r] = e;
        sm[r] += e;
      }
#pragma unroll
    for (int r = 0; r < 4; ++r) {
      sm[r] += __shfl_xor(sm[r], 1);
      sm[r] += __shfl_xor(sm[r], 2);
      sm[r] += __shfl_xor(sm[r], 4);
      sm[r] += __shfl_xor(sm[r], 8);
    }
    float inv[4];
#pragma unroll
    for (int r = 0; r < 4; ++r) inv[r] = 1.f / sm[r];

#pragma unroll
    for (int c = 0; c < 9; ++c)
#pragma unroll
      for (int r = 0; r < 4; ++r)
        Pw[g4 * 4 + r][c * 16 + ln15] = (bf16_t)(lg[c][r] * inv[r]);
#pragma unroll
    for (int z = 0; z < 4; ++z)
      Pw[ln15][144 + g4 * 4 + z] = (bf16_t)0.f;

    bf16x8 paf[5];
#pragma unroll
    for (int c2 = 0; c2 < 5; ++c2)
      paf[c2] = *(const bf16x8*)(&Pw[ln15][c2 * 32 + g4 * 8]);

    f32x4 oacc[4];
#pragma unroll
    for (int j = 0; j < 4; ++j) {
      f32x4 a = {0.f, 0.f, 0.f, 0.f};
#pragma unroll
      for (int c2 = 0; c2 < 5; ++c2)
        a = __builtin_amdgcn_mfma_f32_16x16x32_bf16(paf[c2], vf[j][c2], a, 0, 0, 0);
      oacc[j] = a;
    }
#pragma unroll
    for (int j = 0; j < 4; ++j) {
      const int col = h * cHD + j * 16 + ln15;
#pragma unroll
      for (int r = 0; r < 4; ++r)
        O[((size_t)(b * cP + t0 + g4 * 4 + r)) * cDWM + col] = (bf16_t)oacc[j][r];
    }
  }
}

// ---------------------------------------------------------------------------
extern "C" void kernel_launch(void* const* d_in, const int* in_sizes, int n_in,
                              void* d_out, int out_size, void* d_ws, size_t ws_size,
                              hipStream_t stream) {
  (void)in_sizes; (void)n_in; (void)out_size; (void)ws_size;
  const float* x  = (const float*)d_in[0];
  const int* mask = (const int*)d_in[1];
  const float* Wq = (const float*)d_in[2];
  const float* bq = (const float*)d_in[3];
  const float* Wk = (const float*)d_in[4];
  const float* bk = (const float*)d_in[5];
  const float* Wv = (const float*)d_in[6];
  const float* bv = (const float*)d_in[7];
  const float* Wo = (const float*)d_in[8];
  const float* bo = (const float*)d_in[9];
  float* out = (float*)d_out;

  char* ws = (char*)d_ws;
  size_t off = 0;
  bf16_t* Xbf = (bf16_t*)(ws + off); off += (size_t)cM * cD * 2;          // 64 MiB
  bf16_t* Wqt = (bf16_t*)(ws + off); off += (size_t)cD * cDWM * 2;        // contiguous
  bf16_t* Wkt = (bf16_t*)(ws + off); off += (size_t)cD * cDWM * 2;        //   [2048][1024]
  bf16_t* Wvt = (bf16_t*)(ws + off); off += (size_t)cD * cDWM * 2;
  bf16_t* Wot = (bf16_t*)(ws + off); off += (size_t)cDWM * cD * 2;
  bf16_t* Qh  = (bf16_t*)(ws + off); off += (size_t)cM * cDWM * 2;        // 64 MiB
  bf16_t* Kh  = (bf16_t*)(ws + off); off += (size_t)cM * cDWM * 2;        // 64 MiB
  bf16_t* Vt  = (bf16_t*)(ws + off); off += (size_t)cBS * cH * cHD * cVTP * 2;  // 84 MiB
  int* rbuf   = (int*)(ws + off);    off += (size_t)cBS * cP * 4;
  bf16_t* Ob  = Xbf;  // X no longer needed after the QKV projection

  cvt_x_k<<<2048, 256, 0, stream>>>(x, Xbf, cM * cD);
  cvt_wt_k<<<dim3(32, 32, 4), 256, 0, stream>>>(Wq, Wk, Wv, Wo, Wqt, Wkt, Wvt, Wot);
  resets2_k<<<cBS, cP, 0, stream>>>(mask, rbuf);

  // Q+K fused: 8 XCD x 16 m x 8 nb = 1024 wgs (Wqt|Wkt contiguous B)
  gemm_qk_k<<<dim3(1024), 512, 0, stream>>>(Xbf, Wqt, bq, bk, Qh, Kh);
  // V alone: 512 wgs
  gemm_v_k<<<dim3(512), 512, 0, stream>>>(Xbf, Wvt, bv, Vt);

  attn8_k<<<dim3(cH, cBS, 4), 256, 0, stream>>>(Qh, Kh, Vt, rbuf, Ob);

  // 8 XCD x 16 m-blocks x 4 n-blocks = 512 workgroups of 512
  gemm_bt3_k<<<dim3(512), 512, 0, stream>>>(Ob, Wot, bo, out);
}

// Round 14
// 660.577 us; speedup vs baseline: 1.0170x; 1.0170x over previous
//
#include <hip/hip_runtime.h>
#include <stdint.h>

typedef __bf16 bf16_t;
typedef __bf16 bf16x8 __attribute__((ext_vector_type(8)));
typedef __bf16 bf16x4 __attribute__((ext_vector_type(4)));
typedef float  f32x4  __attribute__((ext_vector_type(4)));

constexpr int cBS = 64, cP = 512, cD = 1024, cDWM = 1024, cH = 16, cHD = 64, cW = 128;
constexpr int cVTP = 672;           // padded p-extent of Vt (sp = p + 128, max used 656)
constexpr int cM = cBS * cP;        // 32768
constexpr float cSCALE = 0.125f;    // 1/sqrt(64)

__device__ __forceinline__ void gld_lds16(const void* g, void* l) {
#if __has_builtin(__builtin_amdgcn_global_load_lds)
  __builtin_amdgcn_global_load_lds(
      (__attribute__((address_space(1))) void*)g,
      (__attribute__((address_space(3))) void*)l, 16, 0, 0);
#else
  *(bf16x8*)l = *(const bf16x8*)g;
#endif
}

// ---------------------------------------------------------------------------
// fp32 -> bf16 conversion of X: 8 elems/thread, 16-B stores, grid-stride.
__global__ void cvt_x_k(const float* __restrict__ X, bf16_t* __restrict__ Y, int n) {
  const int nthreads = gridDim.x * blockDim.x;
  const int n8 = n >> 3;
  for (int i = blockIdx.x * blockDim.x + threadIdx.x; i < n8; i += nthreads) {
    const float4 a = *(const float4*)(X + (size_t)i * 8);
    const float4 b = *(const float4*)(X + (size_t)i * 8 + 4);
    bf16x8 o;
    o[0] = (bf16_t)a.x; o[1] = (bf16_t)a.y; o[2] = (bf16_t)a.z; o[3] = (bf16_t)a.w;
    o[4] = (bf16_t)b.x; o[5] = (bf16_t)b.y; o[6] = (bf16_t)b.z; o[7] = (bf16_t)b.w;
    *(bf16x8*)(Y + (size_t)i * 8) = o;
  }
}

// transpose + convert the four 1024x1024 weights: W[k][n] fp32 -> Wt[n][k] bf16
__global__ void cvt_wt_k(const float* __restrict__ W0, const float* __restrict__ W1,
                         const float* __restrict__ W2, const float* __restrict__ W3,
                         bf16_t* __restrict__ T0, bf16_t* __restrict__ T1,
                         bf16_t* __restrict__ T2, bf16_t* __restrict__ T3) {
  __shared__ float tile[32][33];
  const float* Wsrc; bf16_t* Tdst;
  switch (blockIdx.z) {
    case 0: Wsrc = W0; Tdst = T0; break;
    case 1: Wsrc = W1; Tdst = T1; break;
    case 2: Wsrc = W2; Tdst = T2; break;
    default: Wsrc = W3; Tdst = T3; break;
  }
  const int n0 = blockIdx.x * 32, k0 = blockIdx.y * 32;
  const int c = threadIdx.x & 31, r8 = threadIdx.x >> 5;
#pragma unroll
  for (int q = 0; q < 4; ++q) {
    int row = r8 + q * 8;
    tile[row][c] = Wsrc[(size_t)(k0 + row) * 1024 + n0 + c];
  }
  __syncthreads();
#pragma unroll
  for (int q = 0; q < 4; ++q) {
    int row = r8 + q * 8;
    Tdst[(size_t)(n0 + row) * 1024 + k0 + c] = (bf16_t)tile[c][row];
  }
}

// r[b][t] = index of last reset at-or-before t (0 if none): parallel max-scan
__global__ void resets2_k(const int* __restrict__ mask, int* __restrict__ r) {
  __shared__ int sm[cP];
  const int b = blockIdx.x, t = threadIdx.x;
  sm[t] = mask[b * cP + t] ? t : 0;
  __syncthreads();
#pragma unroll
  for (int d = 1; d < cP; d <<= 1) {
    int u = (t >= d) ? sm[t - d] : 0;
    __syncthreads();
    if (u > sm[t]) sm[t] = u;
    __syncthreads();
  }
  r[b * cP + t] = sm[t];
}

// ---------------------------------------------------------------------------
// 256x256 GEMM core (r2 schedule + r9 nb-slowest order; qk measured
// 140-146 us, MfmaUtil ~44%). One barrier per K-tile; whole next tile
// prefetched into buf^1 (depth-1); fragment reads in two batches interleaved
// with MFMA quadrants; compiler-counted lgkmcnt waits; LDS XOR swizzle
// (bank-conflict-free, verified 0). nb slowest: active 0.5 MiB B-subpanel
// stays L2-hot across 16 consecutive m-blocks. 8-phase counted-vmcnt
// alternative tested r1 (L2-thrash regime) and r13 (L2-hot regime): both
// null-to-negative at this 1-block/CU occupancy — do not revisit.
#define MFMA_B16(a, b, c) c = __builtin_amdgcn_mfma_f32_16x16x32_bf16(a, b, c, 0, 0, 0)

template <int NBLK>
__device__ __forceinline__ void gemm256_core(const bf16_t* __restrict__ A,
                                             const bf16_t* __restrict__ Bt,
                                             bf16_t* __restrict__ LDS,
                                             f32x4 (&acc)[8][4],
                                             int& m0_out, int& n0_out) {
  constexpr int K = 1024;
  bf16_t* Asf = LDS;            // [2][256*64]
  bf16_t* Bsf = LDS + 32768;    // [2][256*64]
  const int tid = threadIdx.x;
  const int wid = tid >> 6, ln = tid & 63;
  const int ln15 = ln & 15, g4 = ln >> 4;
  const int wr = wid >> 2, wc = wid & 3;

  // XCD swizzle, nb slowest: g = xcd + 8*(mloc + 16*nb)
  const int g = blockIdx.x;
  const int xcd = g & 7, s = g >> 3;
  const int nb = s >> 4, mloc = s & 15;
  const int m0 = (xcd * 16 + mloc) * 256, n0 = nb * 256;
  m0_out = m0; n0_out = n0;

  const bf16_t* Ag = A + (size_t)m0 * K;
  const bf16_t* Bg = Bt + (size_t)n0 * K;

  const bf16_t* gsrc[8];
  bf16_t* ldst[8];
#pragma unroll
  for (int sl = 0; sl < 8; ++sl) {
    const int hh = sl >> 1, l = sl & 1;
    const int E = ((hh & 1) << 13) | (l << 12) | (tid << 3);
    const int row = E >> 6;
    const int cg = ((E >> 3) & 7) ^ (row & 7);
    gsrc[sl] = ((hh < 2) ? Ag : Bg) + (size_t)row * K + cg * 8;
    ldst[sl] = ((hh < 2) ? Asf : Bsf) + E;
  }

  const int rA = wr * 128 + ln15;
  const int rB = wc * 64 + ln15;
  const int sA0 = ((g4 ^ (ln15 & 7)) << 3), sA1 = (((4 | g4) ^ (ln15 & 7)) << 3);
  const bf16_t* pA = &Asf[rA * 64];
  const bf16_t* pB = &Bsf[rB * 64];

#pragma unroll
  for (int i = 0; i < 8; ++i)
#pragma unroll
    for (int j = 0; j < 4; ++j) acc[i][j] = {0.f, 0.f, 0.f, 0.f};

#pragma unroll
  for (int sl = 0; sl < 8; ++sl) gld_lds16(gsrc[sl], ldst[sl]);
  asm volatile("s_waitcnt vmcnt(0)" ::: "memory");
  __builtin_amdgcn_sched_barrier(0);
  __builtin_amdgcn_s_barrier();
  __builtin_amdgcn_sched_barrier(0);

  bf16x8 afr[8][2], bfr[4][2];

#pragma unroll 2
  for (int kt = 0; kt < 16; ++kt) {
    const int bo = (kt & 1) << 14;

    if (kt + 1 < 16) {
      const int k0n = (kt + 1) << 6;
      const int bon = ((kt + 1) & 1) << 14;
#pragma unroll
      for (int sl = 0; sl < 8; ++sl) gld_lds16(gsrc[sl] + k0n, ldst[sl] + bon);
    }

    const bf16_t* pAb = pA + bo;
    const bf16_t* pBb = pB + bo;
#pragma unroll
    for (int i = 0; i < 4; ++i) {
      afr[i][0] = *(const bf16x8*)(pAb + i * 1024 + sA0);
      afr[i][1] = *(const bf16x8*)(pAb + i * 1024 + sA1);
    }
#pragma unroll
    for (int j = 0; j < 2; ++j) {
      bfr[j][0] = *(const bf16x8*)(pBb + j * 1024 + sA0);
      bfr[j][1] = *(const bf16x8*)(pBb + j * 1024 + sA1);
    }

#pragma unroll
    for (int i = 0; i < 4; ++i)
#pragma unroll
      for (int j = 0; j < 2; ++j) {
        MFMA_B16(afr[i][0], bfr[j][0], acc[i][j]);
        MFMA_B16(afr[i][1], bfr[j][1], acc[i][j]);
      }

#pragma unroll
    for (int j = 2; j < 4; ++j) {
      bfr[j][0] = *(const bf16x8*)(pBb + j * 1024 + sA0);
      bfr[j][1] = *(const bf16x8*)(pBb + j * 1024 + sA1);
    }
#pragma unroll
    for (int i = 4; i < 8; ++i) {
      afr[i][0] = *(const bf16x8*)(pAb + i * 1024 + sA0);
      afr[i][1] = *(const bf16x8*)(pAb + i * 1024 + sA1);
    }

#pragma unroll
    for (int i = 0; i < 4; ++i)
#pragma unroll
      for (int j = 2; j < 4; ++j) {
        MFMA_B16(afr[i][0], bfr[j][0], acc[i][j]);
        MFMA_B16(afr[i][1], bfr[j][1], acc[i][j]);
      }
#pragma unroll
    for (int i = 4; i < 8; ++i)
#pragma unroll
      for (int j = 2; j < 4; ++j) {
        MFMA_B16(afr[i][0], bfr[j][0], acc[i][j]);
        MFMA_B16(afr[i][1], bfr[j][1], acc[i][j]);
      }
#pragma unroll
    for (int i = 4; i < 8; ++i)
#pragma unroll
      for (int j = 0; j < 2; ++j) {
        MFMA_B16(afr[i][0], bfr[j][0], acc[i][j]);
        MFMA_B16(afr[i][1], bfr[j][1], acc[i][j]);
      }

    asm volatile("s_waitcnt vmcnt(0)" ::: "memory");
    __builtin_amdgcn_sched_barrier(0);
    __builtin_amdgcn_s_barrier();
    __builtin_amdgcn_sched_barrier(0);
  }
}

// Q+K projection: C[32768][2048] = Xbf * Wqk^T (Wqt|Wkt contiguous).
// LDS-restaged epilogue (bf16x8 head-major stores, 128-B segments).
__global__ __launch_bounds__(512, 2)
void gemm_qk_k(const bf16_t* __restrict__ A, const bf16_t* __restrict__ Wt,
               const float* __restrict__ bq, const float* __restrict__ bk,
               bf16_t* __restrict__ Qh, bf16_t* __restrict__ Kh) {
  __shared__ __align__(16) bf16_t LDS[65536];   // 128 KiB
  f32x4 acc[8][4];
  int m0, n0;
  gemm256_core<8>(A, Wt, LDS, acc, m0, n0);

  const int tid = threadIdx.x;
  const int wid = tid >> 6, ln = tid & 63;
  const int ln15 = ln & 15, g4 = ln >> 4;
  const int wr = wid >> 2, wc = wid & 3;

  const int seg = n0 >> 10;                      // block-uniform: 0=Q 1=K
  const float* bias = (seg == 0) ? bq : bk;
  bf16_t* QK = (seg == 0) ? Qh : Kh;
  const int b = m0 >> 9, pb0 = m0 & 511;         // block spans one batch

#pragma unroll
  for (int ci = 0; ci < 4; ++ci) {
#pragma unroll
    for (int i2 = 0; i2 < 2; ++i2) {
      const int i = ci * 2 + i2;
      const int cr = wr * 32 + i2 * 16 + g4 * 4;
#pragma unroll
      for (int j = 0; j < 4; ++j) {
        const int col = wc * 64 + j * 16 + ln15;
        const float bv = bias[(n0 & 1023) + col];
#pragma unroll
        for (int r = 0; r < 4; ++r)
          LDS[(cr + r) * 264 + col] = (bf16_t)(acc[i][j][r] + bv);
      }
    }
    __syncthreads();
#pragma unroll
    for (int k = 0; k < 4; ++k) {
      const int u = k * 512 + tid;
      const int row = u >> 5, cu = u & 31;
      const int wr2 = row >> 5, i2 = (row >> 4) & 1, r16 = row & 15;
      const int pb = pb0 + wr2 * 128 + (ci * 2 + i2) * 16 + r16;
      const int cl = (n0 & 1023) + cu * 8;
      const int h = cl >> 6, hd = cl & 63;
      const bf16x8 v = *(const bf16x8*)(&LDS[row * 264 + cu * 8]);
      *(bf16x8*)(QK + (((size_t)(b * cH + h)) * cP + pb) * cHD + hd) = v;
    }
    __syncthreads();
  }
}

// V projection: Vt transposed layout (bf16x4 stores along p).
__global__ __launch_bounds__(512, 2)
void gemm_v_k(const bf16_t* __restrict__ A, const bf16_t* __restrict__ Wt,
              const float* __restrict__ bias, bf16_t* __restrict__ Vt) {
  __shared__ __align__(16) bf16_t LDS[65536];
  f32x4 acc[8][4];
  int m0, n0;
  gemm256_core<4>(A, Wt, LDS, acc, m0, n0);

  const int tid = threadIdx.x;
  const int wid = tid >> 6, ln = tid & 63;
  const int ln15 = ln & 15, g4 = ln >> 4;
  const int wr = wid >> 2, wc = wid & 3;

#pragma unroll
  for (int i = 0; i < 8; ++i) {
    const int rbase = m0 + wr * 128 + i * 16 + g4 * 4;
    const int b = rbase >> 9, pb = rbase & 511;
#pragma unroll
    for (int j = 0; j < 4; ++j) {
      const int cl = n0 + wc * 64 + j * 16 + ln15;   // [0,1024)
      const int h = cl >> 6, hd = cl & 63;
      const float bv = bias[cl];
      bf16x4 pk;
#pragma unroll
      for (int r = 0; r < 4; ++r) pk[r] = (bf16_t)(acc[i][j][r] + bv);
      *(bf16x4*)(Vt + ((size_t)((b * cH + h) * cHD + hd)) * cVTP + 128 + pb) = pk;
    }
  }
}

// Output projection: C[32768][1024] fp32 = Ob * Wot^T + bo (LDS-restaged;
// each wave writes fully-contiguous 1024-B rows).
__global__ __launch_bounds__(512, 2)
void gemm_bt3_k(const bf16_t* __restrict__ A, const bf16_t* __restrict__ Bt,
                const float* __restrict__ bias, float* __restrict__ C) {
  __shared__ __align__(16) bf16_t LDS[65536];
  f32x4 acc[8][4];
  int m0, n0;
  gemm256_core<4>(A, Bt, LDS, acc, m0, n0);

  const int tid = threadIdx.x;
  const int wid = tid >> 6, ln = tid & 63;
  const int ln15 = ln & 15, g4 = ln >> 4;
  const int wr = wid >> 2, wc = wid & 3;
  float* ldsf = (float*)LDS;                     // [64][264] fp32 staging

#pragma unroll
  for (int ci = 0; ci < 4; ++ci) {
#pragma unroll
    for (int i2 = 0; i2 < 2; ++i2) {
      const int i = ci * 2 + i2;
      const int cr = wr * 32 + i2 * 16 + g4 * 4;
#pragma unroll
      for (int j = 0; j < 4; ++j) {
        const int col = wc * 64 + j * 16 + ln15;
        const float bv = bias[n0 + col];
#pragma unroll
        for (int r = 0; r < 4; ++r)
          ldsf[(cr + r) * 264 + col] = acc[i][j][r] + bv;
      }
    }
    __syncthreads();
#pragma unroll
    for (int k = 0; k < 8; ++k) {
      const int u = k * 512 + tid;
      const int row = u >> 6, cu = u & 63;
      const int wr2 = row >> 5, i2 = (row >> 4) & 1, r16 = row & 15;
      const int grow = m0 + wr2 * 128 + (ci * 2 + i2) * 16 + r16;
      const f32x4 v = *(const f32x4*)(&ldsf[row * 264 + cu * 4]);
      *(f32x4*)(C + (size_t)grow * cD + n0 + cu * 4) = v;
    }
    __syncthreads();
  }
}

// ---------------------------------------------------------------------------
// Windowed attention v8 (best measured attn config): K window staged once
// per block (coalesced, OOB zero-filled); Q/rr for both subs prefetched
// before the barrier; all 20 V-fragments of a sub prefetched into registers
// before that sub's QK^T (HBM latency hides under QK^T+softmax); PV from
// prefetched V regs. Occupancy/structure attacks (r6/r7) and further
// pipelining all measured null-to-negative — latency floor of the serial
// QK^T -> softmax -> PV chain at 2 blocks/CU.
__global__ __launch_bounds__(256, 2)
void attn8_k(const bf16_t* __restrict__ Q, const bf16_t* __restrict__ Kv,
             const bf16_t* __restrict__ Vt, const int* __restrict__ rr,
             bf16_t* __restrict__ O) {
  __shared__ __align__(16) bf16_t Ks[256 * 72];
  __shared__ __align__(16) bf16_t Pl[4][16][168];
  const int tid = threadIdx.x;
  const int wv = tid >> 6, ln = tid & 63, ln15 = ln & 15, g4 = ln >> 4;
  const int h = blockIdx.x, b = blockIdx.y, tc = blockIdx.z;
  bf16_t(*Pw)[168] = Pl[wv];
  const bf16_t* vb = Vt + ((size_t)(b * cH + h)) * cHD * cVTP;
  const bf16_t* qb = Q + ((size_t)(b * cH + h)) * cP * cHD;
  const bf16_t* kb = Kv + ((size_t)(b * cH + h)) * cP * cHD;

  const int kbase = tc * 128 - 128;
#pragma unroll
  for (int p = 0; p < 8; ++p) {
    const int slot = p * 256 + tid;
    const int row = slot >> 3, cg = slot & 7;
    const int s = kbase + row;
    bf16x8 v;
    if ((unsigned)s < (unsigned)cP) {
      v = *(const bf16x8*)(kb + (size_t)s * cHD + cg * 8);
    } else {
#pragma unroll
      for (int z = 0; z < 8; ++z) v[z] = (bf16_t)0.f;
    }
    *(bf16x8*)(Ks + row * 72 + cg * 8) = v;
  }

  const int t00 = tc * 128 + wv * 16;
  const bf16_t* qp0 = qb + (size_t)(t00 + ln15) * cHD + g4 * 8;
  const bf16x8 qa00 = *(const bf16x8*)qp0;
  const bf16x8 qa01 = *(const bf16x8*)(qp0 + 32);
  const bf16_t* qp1 = qp0 + 64 * cHD;
  const bf16x8 qa10 = *(const bf16x8*)qp1;
  const bf16x8 qa11 = *(const bf16x8*)(qp1 + 32);
  const int4 rva = *(const int4*)(rr + b * cP + t00 + g4 * 4);
  const int4 rvb = *(const int4*)(rr + b * cP + t00 + 64 + g4 * 4);

  __syncthreads();

#pragma unroll
  for (int sub = 0; sub < 2; ++sub) {
    const int t0 = t00 + sub * 64;
    const int sbase = t0 - 128;
    const bf16x8 qa0 = sub ? qa10 : qa00;
    const bf16x8 qa1 = sub ? qa11 : qa01;
    const int4 rvv = sub ? rvb : rva;
    const int rv[4] = {rvv.x, rvv.y, rvv.z, rvv.w};

    bf16x8 vf[4][5];
#pragma unroll
    for (int j = 0; j < 4; ++j) {
      const bf16_t* vrow = vb + (size_t)(j * 16 + ln15) * cVTP + t0 + g4 * 8;
#pragma unroll
      for (int c2 = 0; c2 < 5; ++c2) vf[j][c2] = *(const bf16x8*)(vrow + c2 * 32);
    }

    const bf16_t* kls = Ks + (sub * 64 + wv * 16 + ln15) * 72 + g4 * 8;
    f32x4 lg[9];
#pragma unroll
    for (int c = 0; c < 9; ++c) {
      const bf16_t* kp = kls + c * (16 * 72);
      const bf16x8 k0v = *(const bf16x8*)kp;
      const bf16x8 k1v = *(const bf16x8*)(kp + 32);
      f32x4 a = {0.f, 0.f, 0.f, 0.f};
      a = __builtin_amdgcn_mfma_f32_16x16x32_bf16(qa0, k0v, a, 0, 0, 0);
      a = __builtin_amdgcn_mfma_f32_16x16x32_bf16(qa1, k1v, a, 0, 0, 0);
      lg[c] = a;
    }

    float mx[4] = {-1e30f, -1e30f, -1e30f, -1e30f};
#pragma unroll
    for (int c = 0; c < 9; ++c)
#pragma unroll
      for (int r = 0; r < 4; ++r) {
        const int s = sbase + c * 16 + ln15;
        const int t = t0 + g4 * 4 + r;
        const bool ok = (s >= rv[r]) && (s <= t) && (t - s < cW);
        const float l = ok ? lg[c][r] * cSCALE : -1e30f;
        lg[c][r] = l;
        mx[r] = fmaxf(mx[r], l);
      }
#pragma unroll
    for (int r = 0; r < 4; ++r) {
      mx[r] = fmaxf(mx[r], __shfl_xor(mx[r], 1));
      mx[r] = fmaxf(mx[r], __shfl_xor(mx[r], 2));
      mx[r] = fmaxf(mx[r], __shfl_xor(mx[r], 4));
      mx[r] = fmaxf(mx[r], __shfl_xor(mx[r], 8));
    }
    float sm[4] = {0.f, 0.f, 0.f, 0.f};
#pragma unroll
    for (int c = 0; c < 9; ++c)
#pragma unroll
      for (int r = 0; r < 4; ++r) {
        const float e = __expf(lg[c][r] - mx[r]);
        lg[c][r] = e;
        sm[r] += e;
      }
#pragma unroll
    for (int r = 0; r < 4; ++r) {
      sm[r] += __shfl_xor(sm[r], 1);
      sm[r] += __shfl_xor(sm[r], 2);
      sm[r] += __shfl_xor(sm[r], 4);
      sm[r] += __shfl_xor(sm[r], 8);
    }
    float inv[4];
#pragma unroll
    for (int r = 0; r < 4; ++r) inv[r] = 1.f / sm[r];

#pragma unroll
    for (int c = 0; c < 9; ++c)
#pragma unroll
      for (int r = 0; r < 4; ++r)
        Pw[g4 * 4 + r][c * 16 + ln15] = (bf16_t)(lg[c][r] * inv[r]);
#pragma unroll
    for (int z = 0; z < 4; ++z)
      Pw[ln15][144 + g4 * 4 + z] = (bf16_t)0.f;

    bf16x8 paf[5];
#pragma unroll
    for (int c2 = 0; c2 < 5; ++c2)
      paf[c2] = *(const bf16x8*)(&Pw[ln15][c2 * 32 + g4 * 8]);

    f32x4 oacc[4];
#pragma unroll
    for (int j = 0; j < 4; ++j) {
      f32x4 a = {0.f, 0.f, 0.f, 0.f};
#pragma unroll
      for (int c2 = 0; c2 < 5; ++c2)
        a = __builtin_amdgcn_mfma_f32_16x16x32_bf16(paf[c2], vf[j][c2], a, 0, 0, 0);
      oacc[j] = a;
    }
#pragma unroll
    for (int j = 0; j < 4; ++j) {
      const int col = h * cHD + j * 16 + ln15;
#pragma unroll
      for (int r = 0; r < 4; ++r)
        O[((size_t)(b * cP + t0 + g4 * 4 + r)) * cDWM + col] = (bf16_t)oacc[j][r];
    }
  }
}

// ---------------------------------------------------------------------------
extern "C" void kernel_launch(void* const* d_in, const int* in_sizes, int n_in,
                              void* d_out, int out_size, void* d_ws, size_t ws_size,
                              hipStream_t stream) {
  (void)in_sizes; (void)n_in; (void)out_size; (void)ws_size;
  const float* x  = (const float*)d_in[0];
  const int* mask = (const int*)d_in[1];
  const float* Wq = (const float*)d_in[2];
  const float* bq = (const float*)d_in[3];
  const float* Wk = (const float*)d_in[4];
  const float* bk = (const float*)d_in[5];
  const float* Wv = (const float*)d_in[6];
  const float* bv = (const float*)d_in[7];
  const float* Wo = (const float*)d_in[8];
  const float* bo = (const float*)d_in[9];
  float* out = (float*)d_out;

  char* ws = (char*)d_ws;
  size_t off = 0;
  bf16_t* Xbf = (bf16_t*)(ws + off); off += (size_t)cM * cD * 2;          // 64 MiB
  bf16_t* Wqt = (bf16_t*)(ws + off); off += (size_t)cD * cDWM * 2;        // contiguous
  bf16_t* Wkt = (bf16_t*)(ws + off); off += (size_t)cD * cDWM * 2;        //   [2048][1024]
  bf16_t* Wvt = (bf16_t*)(ws + off); off += (size_t)cD * cDWM * 2;
  bf16_t* Wot = (bf16_t*)(ws + off); off += (size_t)cDWM * cD * 2;
  bf16_t* Qh  = (bf16_t*)(ws + off); off += (size_t)cM * cDWM * 2;        // 64 MiB
  bf16_t* Kh  = (bf16_t*)(ws + off); off += (size_t)cM * cDWM * 2;        // 64 MiB
  bf16_t* Vt  = (bf16_t*)(ws + off); off += (size_t)cBS * cH * cHD * cVTP * 2;  // 84 MiB
  int* rbuf   = (int*)(ws + off);    off += (size_t)cBS * cP * 4;
  bf16_t* Ob  = Xbf;  // X no longer needed after the QKV projection

  cvt_x_k<<<2048, 256, 0, stream>>>(x, Xbf, cM * cD);
  cvt_wt_k<<<dim3(32, 32, 4), 256, 0, stream>>>(Wq, Wk, Wv, Wo, Wqt, Wkt, Wvt, Wot);
  resets2_k<<<cBS, cP, 0, stream>>>(mask, rbuf);

  // Q+K fused: 8 XCD x 16 m x 8 nb = 1024 wgs (Wqt|Wkt contiguous B)
  gemm_qk_k<<<dim3(1024), 512, 0, stream>>>(Xbf, Wqt, bq, bk, Qh, Kh);
  // V alone: 512 wgs (written last -> L3-hot for attention)
  gemm_v_k<<<dim3(512), 512, 0, stream>>>(Xbf, Wvt, bv, Vt);

  attn8_k<<<dim3(cH, cBS, 4), 256, 0, stream>>>(Qh, Kh, Vt, rbuf, Ob);

  // 8 XCD x 16 m-blocks x 4 n-blocks = 512 workgroups of 512
  gemm_bt3_k<<<dim3(512), 512, 0, stream>>>(Ob, Wot, bo, out);
}

// Round 15
// 641.520 us; speedup vs baseline: 1.0472x; 1.0297x over previous
//
#include <hip/hip_runtime.h>
#include <stdint.h>

typedef __bf16 bf16_t;
typedef __bf16 bf16x8 __attribute__((ext_vector_type(8)));
typedef __bf16 bf16x4 __attribute__((ext_vector_type(4)));
typedef float  f32x4  __attribute__((ext_vector_type(4)));

constexpr int cBS = 64, cP = 512, cD = 1024, cDWM = 1024, cH = 16, cHD = 64, cW = 128;
constexpr int cVTP = 672;           // padded p-extent of Vt (sp = p + 128, max used 656)
constexpr int cM = cBS * cP;        // 32768
constexpr float cSCALE = 0.125f;    // 1/sqrt(64)

__device__ __forceinline__ void gld_lds16(const void* g, void* l) {
#if __has_builtin(__builtin_amdgcn_global_load_lds)
  __builtin_amdgcn_global_load_lds(
      (__attribute__((address_space(1))) void*)g,
      (__attribute__((address_space(3))) void*)l, 16, 0, 0);
#else
  *(bf16x8*)l = *(const bf16x8*)g;
#endif
}

// ---------------------------------------------------------------------------
// Fused preprocessing: one launch replaces cvt_x + cvt_wt + resets
// (saves two full kernel-boundary drains).
//   blocks [0,2048):      fp32->bf16 X conversion (grid-stride, 16-B stores)
//   blocks [2048,6144):   W transpose+convert (32x32 tiles)
//   blocks [6144,6208):   per-batch reset max-scan (256 thr x 2 elems)
__global__ __launch_bounds__(256)
void pre_k(const float* __restrict__ X, bf16_t* __restrict__ Y,
           const float* __restrict__ W0, const float* __restrict__ W1,
           const float* __restrict__ W2, const float* __restrict__ W3,
           bf16_t* __restrict__ T0, bf16_t* __restrict__ T1,
           bf16_t* __restrict__ T2, bf16_t* __restrict__ T3,
           const int* __restrict__ mask, int* __restrict__ rbuf) {
  __shared__ __align__(16) float shf[32][33];   // cvt_wt tile / resets scan
  const int bid = blockIdx.x;

  if (bid < 2048) {
    // ---- cvt_x: n = cM*cD elements, 8 per thread-iter, stride 2048*256 ----
    constexpr int n8 = (cM * cD) >> 3;
    for (int i = bid * 256 + threadIdx.x; i < n8; i += 2048 * 256) {
      const float4 a = *(const float4*)(X + (size_t)i * 8);
      const float4 b = *(const float4*)(X + (size_t)i * 8 + 4);
      bf16x8 o;
      o[0] = (bf16_t)a.x; o[1] = (bf16_t)a.y; o[2] = (bf16_t)a.z; o[3] = (bf16_t)a.w;
      o[4] = (bf16_t)b.x; o[5] = (bf16_t)b.y; o[6] = (bf16_t)b.z; o[7] = (bf16_t)b.w;
      *(bf16x8*)(Y + (size_t)i * 8) = o;
    }
  } else if (bid < 6144) {
    // ---- cvt_wt: g in [0,4096): bx=g&31 (n0), by=(g>>5)&31 (k0), bz=g>>10 ----
    const int g = bid - 2048;
    const int n0 = (g & 31) * 32, k0 = ((g >> 5) & 31) * 32, bz = g >> 10;
    const float* Wsrc; bf16_t* Tdst;
    switch (bz) {
      case 0: Wsrc = W0; Tdst = T0; break;
      case 1: Wsrc = W1; Tdst = T1; break;
      case 2: Wsrc = W2; Tdst = T2; break;
      default: Wsrc = W3; Tdst = T3; break;
    }
    const int c = threadIdx.x & 31, r8 = threadIdx.x >> 5;
#pragma unroll
    for (int q = 0; q < 4; ++q) {
      int row = r8 + q * 8;
      shf[row][c] = Wsrc[(size_t)(k0 + row) * 1024 + n0 + c];
    }
    __syncthreads();
#pragma unroll
    for (int q = 0; q < 4; ++q) {
      int row = r8 + q * 8;
      Tdst[(size_t)(n0 + row) * 1024 + k0 + c] = (bf16_t)shf[c][row];
    }
  } else {
    // ---- resets: b = bid-6144; inclusive max-scan over 512, 2 elems/thread ----
    int* sm = (int*)&shf[0][0];                  // 512 ints = 2 KiB
    const int b = bid - 6144;
    const int t0 = threadIdx.x, t1 = threadIdx.x + 256;
    sm[t0] = mask[b * cP + t0] ? t0 : 0;
    sm[t1] = mask[b * cP + t1] ? t1 : 0;
    __syncthreads();
#pragma unroll
    for (int d = 1; d < cP; d <<= 1) {
      const int u0 = (t0 >= d) ? sm[t0 - d] : 0;
      const int u1 = (t1 >= d) ? sm[t1 - d] : 0;
      __syncthreads();
      if (u0 > sm[t0]) sm[t0] = u0;
      if (u1 > sm[t1]) sm[t1] = u1;
      __syncthreads();
    }
    rbuf[b * cP + t0] = sm[t0];
    rbuf[b * cP + t1] = sm[t1];
  }
}

// ---------------------------------------------------------------------------
// 256x256 GEMM core (r2 schedule + r9 nb-slowest order; qk measured
// 136-146 us, MfmaUtil ~44%). One barrier per K-tile; whole next tile
// prefetched into buf^1 (depth-1); fragment reads in two batches interleaved
// with MFMA quadrants; compiler-counted lgkmcnt waits; LDS XOR swizzle
// (bank-conflict-free, verified 0). nb slowest: active 0.5 MiB B-subpanel
// stays L2-hot across 16 consecutive m-blocks. 8-phase counted-vmcnt
// alternative tested r1 + r13: null-to-negative at 1 block/CU — do not revisit.
#define MFMA_B16(a, b, c) c = __builtin_amdgcn_mfma_f32_16x16x32_bf16(a, b, c, 0, 0, 0)

template <int NBLK>
__device__ __forceinline__ void gemm256_core(const bf16_t* __restrict__ A,
                                             const bf16_t* __restrict__ Bt,
                                             bf16_t* __restrict__ LDS,
                                             f32x4 (&acc)[8][4],
                                             int& m0_out, int& n0_out) {
  constexpr int K = 1024;
  bf16_t* Asf = LDS;            // [2][256*64]
  bf16_t* Bsf = LDS + 32768;    // [2][256*64]
  const int tid = threadIdx.x;
  const int wid = tid >> 6, ln = tid & 63;
  const int ln15 = ln & 15, g4 = ln >> 4;
  const int wr = wid >> 2, wc = wid & 3;

  // XCD swizzle, nb slowest: g = xcd + 8*(mloc + 16*nb)
  const int g = blockIdx.x;
  const int xcd = g & 7, s = g >> 3;
  const int nb = s >> 4, mloc = s & 15;
  const int m0 = (xcd * 16 + mloc) * 256, n0 = nb * 256;
  m0_out = m0; n0_out = n0;

  const bf16_t* Ag = A + (size_t)m0 * K;
  const bf16_t* Bg = Bt + (size_t)n0 * K;

  const bf16_t* gsrc[8];
  bf16_t* ldst[8];
#pragma unroll
  for (int sl = 0; sl < 8; ++sl) {
    const int hh = sl >> 1, l = sl & 1;
    const int E = ((hh & 1) << 13) | (l << 12) | (tid << 3);
    const int row = E >> 6;
    const int cg = ((E >> 3) & 7) ^ (row & 7);
    gsrc[sl] = ((hh < 2) ? Ag : Bg) + (size_t)row * K + cg * 8;
    ldst[sl] = ((hh < 2) ? Asf : Bsf) + E;
  }

  const int rA = wr * 128 + ln15;
  const int rB = wc * 64 + ln15;
  const int sA0 = ((g4 ^ (ln15 & 7)) << 3), sA1 = (((4 | g4) ^ (ln15 & 7)) << 3);
  const bf16_t* pA = &Asf[rA * 64];
  const bf16_t* pB = &Bsf[rB * 64];

#pragma unroll
  for (int i = 0; i < 8; ++i)
#pragma unroll
    for (int j = 0; j < 4; ++j) acc[i][j] = {0.f, 0.f, 0.f, 0.f};

#pragma unroll
  for (int sl = 0; sl < 8; ++sl) gld_lds16(gsrc[sl], ldst[sl]);
  asm volatile("s_waitcnt vmcnt(0)" ::: "memory");
  __builtin_amdgcn_sched_barrier(0);
  __builtin_amdgcn_s_barrier();
  __builtin_amdgcn_sched_barrier(0);

  bf16x8 afr[8][2], bfr[4][2];

#pragma unroll 2
  for (int kt = 0; kt < 16; ++kt) {
    const int bo = (kt & 1) << 14;

    if (kt + 1 < 16) {
      const int k0n = (kt + 1) << 6;
      const int bon = ((kt + 1) & 1) << 14;
#pragma unroll
      for (int sl = 0; sl < 8; ++sl) gld_lds16(gsrc[sl] + k0n, ldst[sl] + bon);
    }

    const bf16_t* pAb = pA + bo;
    const bf16_t* pBb = pB + bo;
#pragma unroll
    for (int i = 0; i < 4; ++i) {
      afr[i][0] = *(const bf16x8*)(pAb + i * 1024 + sA0);
      afr[i][1] = *(const bf16x8*)(pAb + i * 1024 + sA1);
    }
#pragma unroll
    for (int j = 0; j < 2; ++j) {
      bfr[j][0] = *(const bf16x8*)(pBb + j * 1024 + sA0);
      bfr[j][1] = *(const bf16x8*)(pBb + j * 1024 + sA1);
    }

#pragma unroll
    for (int i = 0; i < 4; ++i)
#pragma unroll
      for (int j = 0; j < 2; ++j) {
        MFMA_B16(afr[i][0], bfr[j][0], acc[i][j]);
        MFMA_B16(afr[i][1], bfr[j][1], acc[i][j]);
      }

#pragma unroll
    for (int j = 2; j < 4; ++j) {
      bfr[j][0] = *(const bf16x8*)(pBb + j * 1024 + sA0);
      bfr[j][1] = *(const bf16x8*)(pBb + j * 1024 + sA1);
    }
#pragma unroll
    for (int i = 4; i < 8; ++i) {
      afr[i][0] = *(const bf16x8*)(pAb + i * 1024 + sA0);
      afr[i][1] = *(const bf16x8*)(pAb + i * 1024 + sA1);
    }

#pragma unroll
    for (int i = 0; i < 4; ++i)
#pragma unroll
      for (int j = 2; j < 4; ++j) {
        MFMA_B16(afr[i][0], bfr[j][0], acc[i][j]);
        MFMA_B16(afr[i][1], bfr[j][1], acc[i][j]);
      }
#pragma unroll
    for (int i = 4; i < 8; ++i)
#pragma unroll
      for (int j = 2; j < 4; ++j) {
        MFMA_B16(afr[i][0], bfr[j][0], acc[i][j]);
        MFMA_B16(afr[i][1], bfr[j][1], acc[i][j]);
      }
#pragma unroll
    for (int i = 4; i < 8; ++i)
#pragma unroll
      for (int j = 0; j < 2; ++j) {
        MFMA_B16(afr[i][0], bfr[j][0], acc[i][j]);
        MFMA_B16(afr[i][1], bfr[j][1], acc[i][j]);
      }

    asm volatile("s_waitcnt vmcnt(0)" ::: "memory");
    __builtin_amdgcn_sched_barrier(0);
    __builtin_amdgcn_s_barrier();
    __builtin_amdgcn_sched_barrier(0);
  }
}

// Q+K projection: C[32768][2048] = Xbf * Wqk^T (Wqt|Wkt contiguous).
// LDS-restaged epilogue (bf16x8 head-major stores, 128-B segments).
__global__ __launch_bounds__(512, 2)
void gemm_qk_k(const bf16_t* __restrict__ A, const bf16_t* __restrict__ Wt,
               const float* __restrict__ bq, const float* __restrict__ bk,
               bf16_t* __restrict__ Qh, bf16_t* __restrict__ Kh) {
  __shared__ __align__(16) bf16_t LDS[65536];   // 128 KiB
  f32x4 acc[8][4];
  int m0, n0;
  gemm256_core<8>(A, Wt, LDS, acc, m0, n0);

  const int tid = threadIdx.x;
  const int wid = tid >> 6, ln = tid & 63;
  const int ln15 = ln & 15, g4 = ln >> 4;
  const int wr = wid >> 2, wc = wid & 3;

  const int seg = n0 >> 10;                      // block-uniform: 0=Q 1=K
  const float* bias = (seg == 0) ? bq : bk;
  bf16_t* QK = (seg == 0) ? Qh : Kh;
  const int b = m0 >> 9, pb0 = m0 & 511;         // block spans one batch

#pragma unroll
  for (int ci = 0; ci < 4; ++ci) {
#pragma unroll
    for (int i2 = 0; i2 < 2; ++i2) {
      const int i = ci * 2 + i2;
      const int cr = wr * 32 + i2 * 16 + g4 * 4;
#pragma unroll
      for (int j = 0; j < 4; ++j) {
        const int col = wc * 64 + j * 16 + ln15;
        const float bv = bias[(n0 & 1023) + col];
#pragma unroll
        for (int r = 0; r < 4; ++r)
          LDS[(cr + r) * 264 + col] = (bf16_t)(acc[i][j][r] + bv);
      }
    }
    __syncthreads();
#pragma unroll
    for (int k = 0; k < 4; ++k) {
      const int u = k * 512 + tid;
      const int row = u >> 5, cu = u & 31;
      const int wr2 = row >> 5, i2 = (row >> 4) & 1, r16 = row & 15;
      const int pb = pb0 + wr2 * 128 + (ci * 2 + i2) * 16 + r16;
      const int cl = (n0 & 1023) + cu * 8;
      const int h = cl >> 6, hd = cl & 63;
      const bf16x8 v = *(const bf16x8*)(&LDS[row * 264 + cu * 8]);
      *(bf16x8*)(QK + (((size_t)(b * cH + h)) * cP + pb) * cHD + hd) = v;
    }
    __syncthreads();
  }
}

// V projection: Vt transposed layout (bf16x4 stores along p).
__global__ __launch_bounds__(512, 2)
void gemm_v_k(const bf16_t* __restrict__ A, const bf16_t* __restrict__ Wt,
              const float* __restrict__ bias, bf16_t* __restrict__ Vt) {
  __shared__ __align__(16) bf16_t LDS[65536];
  f32x4 acc[8][4];
  int m0, n0;
  gemm256_core<4>(A, Wt, LDS, acc, m0, n0);

  const int tid = threadIdx.x;
  const int wid = tid >> 6, ln = tid & 63;
  const int ln15 = ln & 15, g4 = ln >> 4;
  const int wr = wid >> 2, wc = wid & 3;

#pragma unroll
  for (int i = 0; i < 8; ++i) {
    const int rbase = m0 + wr * 128 + i * 16 + g4 * 4;
    const int b = rbase >> 9, pb = rbase & 511;
#pragma unroll
    for (int j = 0; j < 4; ++j) {
      const int cl = n0 + wc * 64 + j * 16 + ln15;   // [0,1024)
      const int h = cl >> 6, hd = cl & 63;
      const float bv = bias[cl];
      bf16x4 pk;
#pragma unroll
      for (int r = 0; r < 4; ++r) pk[r] = (bf16_t)(acc[i][j][r] + bv);
      *(bf16x4*)(Vt + ((size_t)((b * cH + h) * cHD + hd)) * cVTP + 128 + pb) = pk;
    }
  }
}

// Output projection: C[32768][1024] fp32 = Ob * Wot^T + bo (LDS-restaged;
// each wave writes fully-contiguous 1024-B rows).
__global__ __launch_bounds__(512, 2)
void gemm_bt3_k(const bf16_t* __restrict__ A, const bf16_t* __restrict__ Bt,
                const float* __restrict__ bias, float* __restrict__ C) {
  __shared__ __align__(16) bf16_t LDS[65536];
  f32x4 acc[8][4];
  int m0, n0;
  gemm256_core<4>(A, Bt, LDS, acc, m0, n0);

  const int tid = threadIdx.x;
  const int wid = tid >> 6, ln = tid & 63;
  const int ln15 = ln & 15, g4 = ln >> 4;
  const int wr = wid >> 2, wc = wid & 3;
  float* ldsf = (float*)LDS;                     // [64][264] fp32 staging

#pragma unroll
  for (int ci = 0; ci < 4; ++ci) {
#pragma unroll
    for (int i2 = 0; i2 < 2; ++i2) {
      const int i = ci * 2 + i2;
      const int cr = wr * 32 + i2 * 16 + g4 * 4;
#pragma unroll
      for (int j = 0; j < 4; ++j) {
        const int col = wc * 64 + j * 16 + ln15;
        const float bv = bias[n0 + col];
#pragma unroll
        for (int r = 0; r < 4; ++r)
          ldsf[(cr + r) * 264 + col] = acc[i][j][r] + bv;
      }
    }
    __syncthreads();
#pragma unroll
    for (int k = 0; k < 8; ++k) {
      const int u = k * 512 + tid;
      const int row = u >> 6, cu = u & 63;
      const int wr2 = row >> 5, i2 = (row >> 4) & 1, r16 = row & 15;
      const int grow = m0 + wr2 * 128 + (ci * 2 + i2) * 16 + r16;
      const f32x4 v = *(const f32x4*)(&ldsf[row * 264 + cu * 4]);
      *(f32x4*)(C + (size_t)grow * cD + n0 + cu * 4) = v;
    }
    __syncthreads();
  }
}

// ---------------------------------------------------------------------------
// Windowed attention v8 (best measured attn config): K window staged once
// per block (coalesced, OOB zero-filled); Q/rr for both subs prefetched
// before the barrier; all 20 V-fragments of a sub prefetched into registers
// before that sub's QK^T; PV from prefetched V regs.
__global__ __launch_bounds__(256, 2)
void attn8_k(const bf16_t* __restrict__ Q, const bf16_t* __restrict__ Kv,
             const bf16_t* __restrict__ Vt, const int* __restrict__ rr,
             bf16_t* __restrict__ O) {
  __shared__ __align__(16) bf16_t Ks[256 * 72];
  __shared__ __align__(16) bf16_t Pl[4][16][168];
  const int tid = threadIdx.x;
  const int wv = tid >> 6, ln = tid & 63, ln15 = ln & 15, g4 = ln >> 4;
  const int h = blockIdx.x, b = blockIdx.y, tc = blockIdx.z;
  bf16_t(*Pw)[168] = Pl[wv];
  const bf16_t* vb = Vt + ((size_t)(b * cH + h)) * cHD * cVTP;
  const bf16_t* qb = Q + ((size_t)(b * cH + h)) * cP * cHD;
  const bf16_t* kb = Kv + ((size_t)(b * cH + h)) * cP * cHD;

  const int kbase = tc * 128 - 128;
#pragma unroll
  for (int p = 0; p < 8; ++p) {
    const int slot = p * 256 + tid;
    const int row = slot >> 3, cg = slot & 7;
    const int s = kbase + row;
    bf16x8 v;
    if ((unsigned)s < (unsigned)cP) {
      v = *(const bf16x8*)(kb + (size_t)s * cHD + cg * 8);
    } else {
#pragma unroll
      for (int z = 0; z < 8; ++z) v[z] = (bf16_t)0.f;
    }
    *(bf16x8*)(Ks + row * 72 + cg * 8) = v;
  }

  const int t00 = tc * 128 + wv * 16;
  const bf16_t* qp0 = qb + (size_t)(t00 + ln15) * cHD + g4 * 8;
  const bf16x8 qa00 = *(const bf16x8*)qp0;
  const bf16x8 qa01 = *(const bf16x8*)(qp0 + 32);
  const bf16_t* qp1 = qp0 + 64 * cHD;
  const bf16x8 qa10 = *(const bf16x8*)qp1;
  const bf16x8 qa11 = *(const bf16x8*)(qp1 + 32);
  const int4 rva = *(const int4*)(rr + b * cP + t00 + g4 * 4);
  const int4 rvb = *(const int4*)(rr + b * cP + t00 + 64 + g4 * 4);

  __syncthreads();

#pragma unroll
  for (int sub = 0; sub < 2; ++sub) {
    const int t0 = t00 + sub * 64;
    const int sbase = t0 - 128;
    const bf16x8 qa0 = sub ? qa10 : qa00;
    const bf16x8 qa1 = sub ? qa11 : qa01;
    const int4 rvv = sub ? rvb : rva;
    const int rv[4] = {rvv.x, rvv.y, rvv.z, rvv.w};

    bf16x8 vf[4][5];
#pragma unroll
    for (int j = 0; j < 4; ++j) {
      const bf16_t* vrow = vb + (size_t)(j * 16 + ln15) * cVTP + t0 + g4 * 8;
#pragma unroll
      for (int c2 = 0; c2 < 5; ++c2) vf[j][c2] = *(const bf16x8*)(vrow + c2 * 32);
    }

    const bf16_t* kls = Ks + (sub * 64 + wv * 16 + ln15) * 72 + g4 * 8;
    f32x4 lg[9];
#pragma unroll
    for (int c = 0; c < 9; ++c) {
      const bf16_t* kp = kls + c * (16 * 72);
      const bf16x8 k0v = *(const bf16x8*)kp;
      const bf16x8 k1v = *(const bf16x8*)(kp + 32);
      f32x4 a = {0.f, 0.f, 0.f, 0.f};
      a = __builtin_amdgcn_mfma_f32_16x16x32_bf16(qa0, k0v, a, 0, 0, 0);
      a = __builtin_amdgcn_mfma_f32_16x16x32_bf16(qa1, k1v, a, 0, 0, 0);
      lg[c] = a;
    }

    float mx[4] = {-1e30f, -1e30f, -1e30f, -1e30f};
#pragma unroll
    for (int c = 0; c < 9; ++c)
#pragma unroll
      for (int r = 0; r < 4; ++r) {
        const int s = sbase + c * 16 + ln15;
        const int t = t0 + g4 * 4 + r;
        const bool ok = (s >= rv[r]) && (s <= t) && (t - s < cW);
        const float l = ok ? lg[c][r] * cSCALE : -1e30f;
        lg[c][r] = l;
        mx[r] = fmaxf(mx[r], l);
      }
#pragma unroll
    for (int r = 0; r < 4; ++r) {
      mx[r] = fmaxf(mx[r], __shfl_xor(mx[r], 1));
      mx[r] = fmaxf(mx[r], __shfl_xor(mx[r], 2));
      mx[r] = fmaxf(mx[r], __shfl_xor(mx[r], 4));
      mx[r] = fmaxf(mx[r], __shfl_xor(mx[r], 8));
    }
    float sm[4] = {0.f, 0.f, 0.f, 0.f};
#pragma unroll
    for (int c = 0; c < 9; ++c)
#pragma unroll
      for (int r = 0; r < 4; ++r) {
        const float e = __expf(lg[c][r] - mx[r]);
        lg[c][r] = e;
        sm[r] += e;
      }
#pragma unroll
    for (int r = 0; r < 4; ++r) {
      sm[r] += __shfl_xor(sm[r], 1);
      sm[r] += __shfl_xor(sm[r], 2);
      sm[r] += __shfl_xor(sm[r], 4);
      sm[r] += __shfl_xor(sm[r], 8);
    }
    float inv[4];
#pragma unroll
    for (int r = 0; r < 4; ++r) inv[r] = 1.f / sm[r];

#pragma unroll
    for (int c = 0; c < 9; ++c)
#pragma unroll
      for (int r = 0; r < 4; ++r)
        Pw[g4 * 4 + r][c * 16 + ln15] = (bf16_t)(lg[c][r] * inv[r]);
#pragma unroll
    for (int z = 0; z < 4; ++z)
      Pw[ln15][144 + g4 * 4 + z] = (bf16_t)0.f;

    bf16x8 paf[5];
#pragma unroll
    for (int c2 = 0; c2 < 5; ++c2)
      paf[c2] = *(const bf16x8*)(&Pw[ln15][c2 * 32 + g4 * 8]);

    f32x4 oacc[4];
#pragma unroll
    for (int j = 0; j < 4; ++j) {
      f32x4 a = {0.f, 0.f, 0.f, 0.f};
#pragma unroll
      for (int c2 = 0; c2 < 5; ++c2)
        a = __builtin_amdgcn_mfma_f32_16x16x32_bf16(paf[c2], vf[j][c2], a, 0, 0, 0);
      oacc[j] = a;
    }
#pragma unroll
    for (int j = 0; j < 4; ++j) {
      const int col = h * cHD + j * 16 + ln15;
#pragma unroll
      for (int r = 0; r < 4; ++r)
        O[((size_t)(b * cP + t0 + g4 * 4 + r)) * cDWM + col] = (bf16_t)oacc[j][r];
    }
  }
}

// ---------------------------------------------------------------------------
extern "C" void kernel_launch(void* const* d_in, const int* in_sizes, int n_in,
                              void* d_out, int out_size, void* d_ws, size_t ws_size,
                              hipStream_t stream) {
  (void)in_sizes; (void)n_in; (void)out_size; (void)ws_size;
  const float* x  = (const float*)d_in[0];
  const int* mask = (const int*)d_in[1];
  const float* Wq = (const float*)d_in[2];
  const float* bq = (const float*)d_in[3];
  const float* Wk = (const float*)d_in[4];
  const float* bk = (const float*)d_in[5];
  const float* Wv = (const float*)d_in[6];
  const float* bv = (const float*)d_in[7];
  const float* Wo = (const float*)d_in[8];
  const float* bo = (const float*)d_in[9];
  float* out = (float*)d_out;

  char* ws = (char*)d_ws;
  size_t off = 0;
  bf16_t* Xbf = (bf16_t*)(ws + off); off += (size_t)cM * cD * 2;          // 64 MiB
  bf16_t* Wqt = (bf16_t*)(ws + off); off += (size_t)cD * cDWM * 2;        // contiguous
  bf16_t* Wkt = (bf16_t*)(ws + off); off += (size_t)cD * cDWM * 2;        //   [2048][1024]
  bf16_t* Wvt = (bf16_t*)(ws + off); off += (size_t)cD * cDWM * 2;
  bf16_t* Wot = (bf16_t*)(ws + off); off += (size_t)cDWM * cD * 2;
  bf16_t* Qh  = (bf16_t*)(ws + off); off += (size_t)cM * cDWM * 2;        // 64 MiB
  bf16_t* Kh  = (bf16_t*)(ws + off); off += (size_t)cM * cDWM * 2;        // 64 MiB
  bf16_t* Vt  = (bf16_t*)(ws + off); off += (size_t)cBS * cH * cHD * cVTP * 2;  // 84 MiB
  int* rbuf   = (int*)(ws + off);    off += (size_t)cBS * cP * 4;
  bf16_t* Ob  = Xbf;  // X no longer needed after the QKV projection

  // Fused preprocessing: cvt_x (2048) + cvt_wt (4096) + resets (64)
  pre_k<<<dim3(6208), 256, 0, stream>>>(x, Xbf, Wq, Wk, Wv, Wo,
                                        Wqt, Wkt, Wvt, Wot, mask, rbuf);

  // Q+K fused: 8 XCD x 16 m x 8 nb = 1024 wgs (Wqt|Wkt contiguous B)
  gemm_qk_k<<<dim3(1024), 512, 0, stream>>>(Xbf, Wqt, bq, bk, Qh, Kh);
  // V alone: 512 wgs (written last -> L3-hot for attention)
  gemm_v_k<<<dim3(512), 512, 0, stream>>>(Xbf, Wvt, bv, Vt);

  attn8_k<<<dim3(cH, cBS, 4), 256, 0, stream>>>(Qh, Kh, Vt, rbuf, Ob);

  // 8 XCD x 16 m-blocks x 4 n-blocks = 512 workgroups of 512
  gemm_bt3_k<<<dim3(512), 512, 0, stream>>>(Ob, Wot, bo, out);
}

// Round 16
// 632.424 us; speedup vs baseline: 1.0623x; 1.0144x over previous
//
#include <hip/hip_runtime.h>
#include <stdint.h>

typedef __bf16 bf16_t;
typedef __bf16 bf16x8 __attribute__((ext_vector_type(8)));
typedef __bf16 bf16x4 __attribute__((ext_vector_type(4)));
typedef float  f32x4  __attribute__((ext_vector_type(4)));

constexpr int cBS = 64, cP = 512, cD = 1024, cDWM = 1024, cH = 16, cHD = 64, cW = 128;
constexpr int cVTP = 672;           // padded p-extent of Vt (sp = p + 128, max used 656)
constexpr int cM = cBS * cP;        // 32768
constexpr float cSCALE = 0.125f;    // 1/sqrt(64)

__device__ __forceinline__ void gld_lds16(const void* g, void* l) {
#if __has_builtin(__builtin_amdgcn_global_load_lds)
  __builtin_amdgcn_global_load_lds(
      (__attribute__((address_space(1))) void*)g,
      (__attribute__((address_space(3))) void*)l, 16, 0, 0);
#else
  *(bf16x8*)l = *(const bf16x8*)g;
#endif
}

// ---------------------------------------------------------------------------
// Fused preprocessing: one launch replaces cvt_x + cvt_wt + resets.
//   blocks [0,2048):      fp32->bf16 X conversion (grid-stride, 16-B stores)
//   blocks [2048,6144):   W transpose+convert (32x32 tiles)
//   blocks [6144,6208):   per-batch reset max-scan (256 thr x 2 elems)
__global__ __launch_bounds__(256)
void pre_k(const float* __restrict__ X, bf16_t* __restrict__ Y,
           const float* __restrict__ W0, const float* __restrict__ W1,
           const float* __restrict__ W2, const float* __restrict__ W3,
           bf16_t* __restrict__ T0, bf16_t* __restrict__ T1,
           bf16_t* __restrict__ T2, bf16_t* __restrict__ T3,
           const int* __restrict__ mask, int* __restrict__ rbuf) {
  __shared__ __align__(16) float shf[32][33];   // cvt_wt tile / resets scan
  const int bid = blockIdx.x;

  if (bid < 2048) {
    constexpr int n8 = (cM * cD) >> 3;
    for (int i = bid * 256 + threadIdx.x; i < n8; i += 2048 * 256) {
      const float4 a = *(const float4*)(X + (size_t)i * 8);
      const float4 b = *(const float4*)(X + (size_t)i * 8 + 4);
      bf16x8 o;
      o[0] = (bf16_t)a.x; o[1] = (bf16_t)a.y; o[2] = (bf16_t)a.z; o[3] = (bf16_t)a.w;
      o[4] = (bf16_t)b.x; o[5] = (bf16_t)b.y; o[6] = (bf16_t)b.z; o[7] = (bf16_t)b.w;
      *(bf16x8*)(Y + (size_t)i * 8) = o;
    }
  } else if (bid < 6144) {
    const int g = bid - 2048;
    const int n0 = (g & 31) * 32, k0 = ((g >> 5) & 31) * 32, bz = g >> 10;
    const float* Wsrc; bf16_t* Tdst;
    switch (bz) {
      case 0: Wsrc = W0; Tdst = T0; break;
      case 1: Wsrc = W1; Tdst = T1; break;
      case 2: Wsrc = W2; Tdst = T2; break;
      default: Wsrc = W3; Tdst = T3; break;
    }
    const int c = threadIdx.x & 31, r8 = threadIdx.x >> 5;
#pragma unroll
    for (int q = 0; q < 4; ++q) {
      int row = r8 + q * 8;
      shf[row][c] = Wsrc[(size_t)(k0 + row) * 1024 + n0 + c];
    }
    __syncthreads();
#pragma unroll
    for (int q = 0; q < 4; ++q) {
      int row = r8 + q * 8;
      Tdst[(size_t)(n0 + row) * 1024 + k0 + c] = (bf16_t)shf[c][row];
    }
  } else {
    int* sm = (int*)&shf[0][0];                  // 512 ints = 2 KiB
    const int b = bid - 6144;
    const int t0 = threadIdx.x, t1 = threadIdx.x + 256;
    sm[t0] = mask[b * cP + t0] ? t0 : 0;
    sm[t1] = mask[b * cP + t1] ? t1 : 0;
    __syncthreads();
#pragma unroll
    for (int d = 1; d < cP; d <<= 1) {
      const int u0 = (t0 >= d) ? sm[t0 - d] : 0;
      const int u1 = (t1 >= d) ? sm[t1 - d] : 0;
      __syncthreads();
      if (u0 > sm[t0]) sm[t0] = u0;
      if (u1 > sm[t1]) sm[t1] = u1;
      __syncthreads();
    }
    rbuf[b * cP + t0] = sm[t0];
    rbuf[b * cP + t1] = sm[t1];
  }
}

// ---------------------------------------------------------------------------
// 256x256 GEMM core (r2 schedule + r9 nb-slowest order; qk measured
// 136-146 us, MfmaUtil ~44%). One barrier per K-tile; whole next tile
// prefetched into buf^1 (depth-1); fragment reads in two batches interleaved
// with MFMA quadrants; compiler-counted lgkmcnt waits; LDS XOR swizzle
// (bank-conflict-free, verified 0). nb slowest: active 0.5 MiB B-subpanel
// stays L2-hot across 16 consecutive m-blocks. g passed by caller (merged
// qk|v launch maps its own block ranges).
#define MFMA_B16(a, b, c) c = __builtin_amdgcn_mfma_f32_16x16x32_bf16(a, b, c, 0, 0, 0)

template <int NBLK>
__device__ __forceinline__ void gemm256_core(const bf16_t* __restrict__ A,
                                             const bf16_t* __restrict__ Bt,
                                             bf16_t* __restrict__ LDS, int g,
                                             f32x4 (&acc)[8][4],
                                             int& m0_out, int& n0_out) {
  constexpr int K = 1024;
  bf16_t* Asf = LDS;            // [2][256*64]
  bf16_t* Bsf = LDS + 32768;    // [2][256*64]
  const int tid = threadIdx.x;
  const int wid = tid >> 6, ln = tid & 63;
  const int ln15 = ln & 15, g4 = ln >> 4;
  const int wr = wid >> 2, wc = wid & 3;

  // XCD swizzle, nb slowest: g = xcd + 8*(mloc + 16*nb)
  const int xcd = g & 7, s = g >> 3;
  const int nb = s >> 4, mloc = s & 15;
  const int m0 = (xcd * 16 + mloc) * 256, n0 = nb * 256;
  m0_out = m0; n0_out = n0;

  const bf16_t* Ag = A + (size_t)m0 * K;
  const bf16_t* Bg = Bt + (size_t)n0 * K;

  const bf16_t* gsrc[8];
  bf16_t* ldst[8];
#pragma unroll
  for (int sl = 0; sl < 8; ++sl) {
    const int hh = sl >> 1, l = sl & 1;
    const int E = ((hh & 1) << 13) | (l << 12) | (tid << 3);
    const int row = E >> 6;
    const int cg = ((E >> 3) & 7) ^ (row & 7);
    gsrc[sl] = ((hh < 2) ? Ag : Bg) + (size_t)row * K + cg * 8;
    ldst[sl] = ((hh < 2) ? Asf : Bsf) + E;
  }

  const int rA = wr * 128 + ln15;
  const int rB = wc * 64 + ln15;
  const int sA0 = ((g4 ^ (ln15 & 7)) << 3), sA1 = (((4 | g4) ^ (ln15 & 7)) << 3);
  const bf16_t* pA = &Asf[rA * 64];
  const bf16_t* pB = &Bsf[rB * 64];

#pragma unroll
  for (int i = 0; i < 8; ++i)
#pragma unroll
    for (int j = 0; j < 4; ++j) acc[i][j] = {0.f, 0.f, 0.f, 0.f};

#pragma unroll
  for (int sl = 0; sl < 8; ++sl) gld_lds16(gsrc[sl], ldst[sl]);
  asm volatile("s_waitcnt vmcnt(0)" ::: "memory");
  __builtin_amdgcn_sched_barrier(0);
  __builtin_amdgcn_s_barrier();
  __builtin_amdgcn_sched_barrier(0);

  bf16x8 afr[8][2], bfr[4][2];

#pragma unroll 2
  for (int kt = 0; kt < 16; ++kt) {
    const int bo = (kt & 1) << 14;

    if (kt + 1 < 16) {
      const int k0n = (kt + 1) << 6;
      const int bon = ((kt + 1) & 1) << 14;
#pragma unroll
      for (int sl = 0; sl < 8; ++sl) gld_lds16(gsrc[sl] + k0n, ldst[sl] + bon);
    }

    const bf16_t* pAb = pA + bo;
    const bf16_t* pBb = pB + bo;
#pragma unroll
    for (int i = 0; i < 4; ++i) {
      afr[i][0] = *(const bf16x8*)(pAb + i * 1024 + sA0);
      afr[i][1] = *(const bf16x8*)(pAb + i * 1024 + sA1);
    }
#pragma unroll
    for (int j = 0; j < 2; ++j) {
      bfr[j][0] = *(const bf16x8*)(pBb + j * 1024 + sA0);
      bfr[j][1] = *(const bf16x8*)(pBb + j * 1024 + sA1);
    }

#pragma unroll
    for (int i = 0; i < 4; ++i)
#pragma unroll
      for (int j = 0; j < 2; ++j) {
        MFMA_B16(afr[i][0], bfr[j][0], acc[i][j]);
        MFMA_B16(afr[i][1], bfr[j][1], acc[i][j]);
      }

#pragma unroll
    for (int j = 2; j < 4; ++j) {
      bfr[j][0] = *(const bf16x8*)(pBb + j * 1024 + sA0);
      bfr[j][1] = *(const bf16x8*)(pBb + j * 1024 + sA1);
    }
#pragma unroll
    for (int i = 4; i < 8; ++i) {
      afr[i][0] = *(const bf16x8*)(pAb + i * 1024 + sA0);
      afr[i][1] = *(const bf16x8*)(pAb + i * 1024 + sA1);
    }

#pragma unroll
    for (int i = 0; i < 4; ++i)
#pragma unroll
      for (int j = 2; j < 4; ++j) {
        MFMA_B16(afr[i][0], bfr[j][0], acc[i][j]);
        MFMA_B16(afr[i][1], bfr[j][1], acc[i][j]);
      }
#pragma unroll
    for (int i = 4; i < 8; ++i)
#pragma unroll
      for (int j = 2; j < 4; ++j) {
        MFMA_B16(afr[i][0], bfr[j][0], acc[i][j]);
        MFMA_B16(afr[i][1], bfr[j][1], acc[i][j]);
      }
#pragma unroll
    for (int i = 4; i < 8; ++i)
#pragma unroll
      for (int j = 0; j < 2; ++j) {
        MFMA_B16(afr[i][0], bfr[j][0], acc[i][j]);
        MFMA_B16(afr[i][1], bfr[j][1], acc[i][j]);
      }

    asm volatile("s_waitcnt vmcnt(0)" ::: "memory");
    __builtin_amdgcn_sched_barrier(0);
    __builtin_amdgcn_s_barrier();
    __builtin_amdgcn_sched_barrier(0);
  }
}

// ---------------------------------------------------------------------------
// Merged QKV projection: one launch of 1536 blocks.
//   blocks [0,1024):    Q+K GEMM (Wqt|Wkt contiguous B, NBLK=8, LDS-restaged
//                       head-major bf16x8 epilogue)
//   blocks [1024,1536): V GEMM (NBLK=4, Vt transposed bf16x4 epilogue)
// qk blocks dispatch first (same order as the previous two launches); the
// merge removes one device-wide drain plus qk's ragged tail round.
__global__ __launch_bounds__(512, 2)
void gemm_qkv_k(const bf16_t* __restrict__ A, const bf16_t* __restrict__ Wqk,
                const bf16_t* __restrict__ Wv,
                const float* __restrict__ bq, const float* __restrict__ bk,
                const float* __restrict__ bvv,
                bf16_t* __restrict__ Qh, bf16_t* __restrict__ Kh,
                bf16_t* __restrict__ Vt) {
  __shared__ __align__(16) bf16_t LDS[65536];   // 128 KiB
  f32x4 acc[8][4];
  int m0, n0;

  const int tid = threadIdx.x;
  const int wid = tid >> 6, ln = tid & 63;
  const int ln15 = ln & 15, g4 = ln >> 4;
  const int wr = wid >> 2, wc = wid & 3;

  if (blockIdx.x < 1024) {
    // ---- Q+K path ----
    gemm256_core<8>(A, Wqk, LDS, blockIdx.x, acc, m0, n0);

    const int seg = n0 >> 10;                    // block-uniform: 0=Q 1=K
    const float* bias = (seg == 0) ? bq : bk;
    bf16_t* QK = (seg == 0) ? Qh : Kh;
    const int b = m0 >> 9, pb0 = m0 & 511;       // block spans one batch

#pragma unroll
    for (int ci = 0; ci < 4; ++ci) {
#pragma unroll
      for (int i2 = 0; i2 < 2; ++i2) {
        const int i = ci * 2 + i2;
        const int cr = wr * 32 + i2 * 16 + g4 * 4;
#pragma unroll
        for (int j = 0; j < 4; ++j) {
          const int col = wc * 64 + j * 16 + ln15;
          const float bv = bias[(n0 & 1023) + col];
#pragma unroll
          for (int r = 0; r < 4; ++r)
            LDS[(cr + r) * 264 + col] = (bf16_t)(acc[i][j][r] + bv);
        }
      }
      __syncthreads();
#pragma unroll
      for (int k = 0; k < 4; ++k) {
        const int u = k * 512 + tid;
        const int row = u >> 5, cu = u & 31;
        const int wr2 = row >> 5, i2 = (row >> 4) & 1, r16 = row & 15;
        const int pb = pb0 + wr2 * 128 + (ci * 2 + i2) * 16 + r16;
        const int cl = (n0 & 1023) + cu * 8;
        const int h = cl >> 6, hd = cl & 63;
        const bf16x8 v = *(const bf16x8*)(&LDS[row * 264 + cu * 8]);
        *(bf16x8*)(QK + (((size_t)(b * cH + h)) * cP + pb) * cHD + hd) = v;
      }
      __syncthreads();
    }
  } else {
    // ---- V path ----
    gemm256_core<4>(A, Wv, LDS, blockIdx.x - 1024, acc, m0, n0);

#pragma unroll
    for (int i = 0; i < 8; ++i) {
      const int rbase = m0 + wr * 128 + i * 16 + g4 * 4;
      const int b = rbase >> 9, pb = rbase & 511;
#pragma unroll
      for (int j = 0; j < 4; ++j) {
        const int cl = n0 + wc * 64 + j * 16 + ln15;   // [0,1024)
        const int h = cl >> 6, hd = cl & 63;
        const float bv = bvv[cl];
        bf16x4 pk;
#pragma unroll
        for (int r = 0; r < 4; ++r) pk[r] = (bf16_t)(acc[i][j][r] + bv);
        *(bf16x4*)(Vt + ((size_t)((b * cH + h) * cHD + hd)) * cVTP + 128 + pb) = pk;
      }
    }
  }
}

// Output projection: C[32768][1024] fp32 = Ob * Wot^T + bo (LDS-restaged;
// each wave writes fully-contiguous 1024-B rows).
__global__ __launch_bounds__(512, 2)
void gemm_bt3_k(const bf16_t* __restrict__ A, const bf16_t* __restrict__ Bt,
                const float* __restrict__ bias, float* __restrict__ C) {
  __shared__ __align__(16) bf16_t LDS[65536];
  f32x4 acc[8][4];
  int m0, n0;
  gemm256_core<4>(A, Bt, LDS, blockIdx.x, acc, m0, n0);

  const int tid = threadIdx.x;
  const int wid = tid >> 6, ln = tid & 63;
  const int ln15 = ln & 15, g4 = ln >> 4;
  const int wr = wid >> 2, wc = wid & 3;
  float* ldsf = (float*)LDS;                     // [64][264] fp32 staging

#pragma unroll
  for (int ci = 0; ci < 4; ++ci) {
#pragma unroll
    for (int i2 = 0; i2 < 2; ++i2) {
      const int i = ci * 2 + i2;
      const int cr = wr * 32 + i2 * 16 + g4 * 4;
#pragma unroll
      for (int j = 0; j < 4; ++j) {
        const int col = wc * 64 + j * 16 + ln15;
        const float bv = bias[n0 + col];
#pragma unroll
        for (int r = 0; r < 4; ++r)
          ldsf[(cr + r) * 264 + col] = acc[i][j][r] + bv;
      }
    }
    __syncthreads();
#pragma unroll
    for (int k = 0; k < 8; ++k) {
      const int u = k * 512 + tid;
      const int row = u >> 6, cu = u & 63;
      const int wr2 = row >> 5, i2 = (row >> 4) & 1, r16 = row & 15;
      const int grow = m0 + wr2 * 128 + (ci * 2 + i2) * 16 + r16;
      const f32x4 v = *(const f32x4*)(&ldsf[row * 264 + cu * 4]);
      *(f32x4*)(C + (size_t)grow * cD + n0 + cu * 4) = v;
    }
    __syncthreads();
  }
}

// ---------------------------------------------------------------------------
// Windowed attention v8 (best measured attn config): K window staged once
// per block (coalesced, OOB zero-filled); Q/rr for both subs prefetched
// before the barrier; all 20 V-fragments of a sub prefetched into registers
// before that sub's QK^T; PV from prefetched V regs.
__global__ __launch_bounds__(256, 2)
void attn8_k(const bf16_t* __restrict__ Q, const bf16_t* __restrict__ Kv,
             const bf16_t* __restrict__ Vt, const int* __restrict__ rr,
             bf16_t* __restrict__ O) {
  __shared__ __align__(16) bf16_t Ks[256 * 72];
  __shared__ __align__(16) bf16_t Pl[4][16][168];
  const int tid = threadIdx.x;
  const int wv = tid >> 6, ln = tid & 63, ln15 = ln & 15, g4 = ln >> 4;
  const int h = blockIdx.x, b = blockIdx.y, tc = blockIdx.z;
  bf16_t(*Pw)[168] = Pl[wv];
  const bf16_t* vb = Vt + ((size_t)(b * cH + h)) * cHD * cVTP;
  const bf16_t* qb = Q + ((size_t)(b * cH + h)) * cP * cHD;
  const bf16_t* kb = Kv + ((size_t)(b * cH + h)) * cP * cHD;

  const int kbase = tc * 128 - 128;
#pragma unroll
  for (int p = 0; p < 8; ++p) {
    const int slot = p * 256 + tid;
    const int row = slot >> 3, cg = slot & 7;
    const int s = kbase + row;
    bf16x8 v;
    if ((unsigned)s < (unsigned)cP) {
      v = *(const bf16x8*)(kb + (size_t)s * cHD + cg * 8);
    } else {
#pragma unroll
      for (int z = 0; z < 8; ++z) v[z] = (bf16_t)0.f;
    }
    *(bf16x8*)(Ks + row * 72 + cg * 8) = v;
  }

  const int t00 = tc * 128 + wv * 16;
  const bf16_t* qp0 = qb + (size_t)(t00 + ln15) * cHD + g4 * 8;
  const bf16x8 qa00 = *(const bf16x8*)qp0;
  const bf16x8 qa01 = *(const bf16x8*)(qp0 + 32);
  const bf16_t* qp1 = qp0 + 64 * cHD;
  const bf16x8 qa10 = *(const bf16x8*)qp1;
  const bf16x8 qa11 = *(const bf16x8*)(qp1 + 32);
  const int4 rva = *(const int4*)(rr + b * cP + t00 + g4 * 4);
  const int4 rvb = *(const int4*)(rr + b * cP + t00 + 64 + g4 * 4);

  __syncthreads();

#pragma unroll
  for (int sub = 0; sub < 2; ++sub) {
    const int t0 = t00 + sub * 64;
    const int sbase = t0 - 128;
    const bf16x8 qa0 = sub ? qa10 : qa00;
    const bf16x8 qa1 = sub ? qa11 : qa01;
    const int4 rvv = sub ? rvb : rva;
    const int rv[4] = {rvv.x, rvv.y, rvv.z, rvv.w};

    bf16x8 vf[4][5];
#pragma unroll
    for (int j = 0; j < 4; ++j) {
      const bf16_t* vrow = vb + (size_t)(j * 16 + ln15) * cVTP + t0 + g4 * 8;
#pragma unroll
      for (int c2 = 0; c2 < 5; ++c2) vf[j][c2] = *(const bf16x8*)(vrow + c2 * 32);
    }

    const bf16_t* kls = Ks + (sub * 64 + wv * 16 + ln15) * 72 + g4 * 8;
    f32x4 lg[9];
#pragma unroll
    for (int c = 0; c < 9; ++c) {
      const bf16_t* kp = kls + c * (16 * 72);
      const bf16x8 k0v = *(const bf16x8*)kp;
      const bf16x8 k1v = *(const bf16x8*)(kp + 32);
      f32x4 a = {0.f, 0.f, 0.f, 0.f};
      a = __builtin_amdgcn_mfma_f32_16x16x32_bf16(qa0, k0v, a, 0, 0, 0);
      a = __builtin_amdgcn_mfma_f32_16x16x32_bf16(qa1, k1v, a, 0, 0, 0);
      lg[c] = a;
    }

    float mx[4] = {-1e30f, -1e30f, -1e30f, -1e30f};
#pragma unroll
    for (int c = 0; c < 9; ++c)
#pragma unroll
      for (int r = 0; r < 4; ++r) {
        const int s = sbase + c * 16 + ln15;
        const int t = t0 + g4 * 4 + r;
        const bool ok = (s >= rv[r]) && (s <= t) && (t - s < cW);
        const float l = ok ? lg[c][r] * cSCALE : -1e30f;
        lg[c][r] = l;
        mx[r] = fmaxf(mx[r], l);
      }
#pragma unroll
    for (int r = 0; r < 4; ++r) {
      mx[r] = fmaxf(mx[r], __shfl_xor(mx[r], 1));
      mx[r] = fmaxf(mx[r], __shfl_xor(mx[r], 2));
      mx[r] = fmaxf(mx[r], __shfl_xor(mx[r], 4));
      mx[r] = fmaxf(mx[r], __shfl_xor(mx[r], 8));
    }
    float sm[4] = {0.f, 0.f, 0.f, 0.f};
#pragma unroll
    for (int c = 0; c < 9; ++c)
#pragma unroll
      for (int r = 0; r < 4; ++r) {
        const float e = __expf(lg[c][r] - mx[r]);
        lg[c][r] = e;
        sm[r] += e;
      }
#pragma unroll
    for (int r = 0; r < 4; ++r) {
      sm[r] += __shfl_xor(sm[r], 1);
      sm[r] += __shfl_xor(sm[r], 2);
      sm[r] += __shfl_xor(sm[r], 4);
      sm[r] += __shfl_xor(sm[r], 8);
    }
    float inv[4];
#pragma unroll
    for (int r = 0; r < 4; ++r) inv[r] = 1.f / sm[r];

#pragma unroll
    for (int c = 0; c < 9; ++c)
#pragma unroll
      for (int r = 0; r < 4; ++r)
        Pw[g4 * 4 + r][c * 16 + ln15] = (bf16_t)(lg[c][r] * inv[r]);
#pragma unroll
    for (int z = 0; z < 4; ++z)
      Pw[ln15][144 + g4 * 4 + z] = (bf16_t)0.f;

    bf16x8 paf[5];
#pragma unroll
    for (int c2 = 0; c2 < 5; ++c2)
      paf[c2] = *(const bf16x8*)(&Pw[ln15][c2 * 32 + g4 * 8]);

    f32x4 oacc[4];
#pragma unroll
    for (int j = 0; j < 4; ++j) {
      f32x4 a = {0.f, 0.f, 0.f, 0.f};
#pragma unroll
      for (int c2 = 0; c2 < 5; ++c2)
        a = __builtin_amdgcn_mfma_f32_16x16x32_bf16(paf[c2], vf[j][c2], a, 0, 0, 0);
      oacc[j] = a;
    }
#pragma unroll
    for (int j = 0; j < 4; ++j) {
      const int col = h * cHD + j * 16 + ln15;
#pragma unroll
      for (int r = 0; r < 4; ++r)
        O[((size_t)(b * cP + t0 + g4 * 4 + r)) * cDWM + col] = (bf16_t)oacc[j][r];
    }
  }
}

// ---------------------------------------------------------------------------
extern "C" void kernel_launch(void* const* d_in, const int* in_sizes, int n_in,
                              void* d_out, int out_size, void* d_ws, size_t ws_size,
                              hipStream_t stream) {
  (void)in_sizes; (void)n_in; (void)out_size; (void)ws_size;
  const float* x  = (const float*)d_in[0];
  const int* mask = (const int*)d_in[1];
  const float* Wq = (const float*)d_in[2];
  const float* bq = (const float*)d_in[3];
  const float* Wk = (const float*)d_in[4];
  const float* bk = (const float*)d_in[5];
  const float* Wv = (const float*)d_in[6];
  const float* bv = (const float*)d_in[7];
  const float* Wo = (const float*)d_in[8];
  const float* bo = (const float*)d_in[9];
  float* out = (float*)d_out;

  char* ws = (char*)d_ws;
  size_t off = 0;
  bf16_t* Xbf = (bf16_t*)(ws + off); off += (size_t)cM * cD * 2;          // 64 MiB
  bf16_t* Wqt = (bf16_t*)(ws + off); off += (size_t)cD * cDWM * 2;        // contiguous
  bf16_t* Wkt = (bf16_t*)(ws + off); off += (size_t)cD * cDWM * 2;        //   [2048][1024]
  bf16_t* Wvt = (bf16_t*)(ws + off); off += (size_t)cD * cDWM * 2;
  bf16_t* Wot = (bf16_t*)(ws + off); off += (size_t)cDWM * cD * 2;
  bf16_t* Qh  = (bf16_t*)(ws + off); off += (size_t)cM * cDWM * 2;        // 64 MiB
  bf16_t* Kh  = (bf16_t*)(ws + off); off += (size_t)cM * cDWM * 2;        // 64 MiB
  bf16_t* Vt  = (bf16_t*)(ws + off); off += (size_t)cBS * cH * cHD * cVTP * 2;  // 84 MiB
  int* rbuf   = (int*)(ws + off);    off += (size_t)cBS * cP * 4;
  bf16_t* Ob  = Xbf;  // X no longer needed after the QKV projection

  // Fused preprocessing: cvt_x (2048) + cvt_wt (4096) + resets (64)
  pre_k<<<dim3(6208), 256, 0, stream>>>(x, Xbf, Wq, Wk, Wv, Wo,
                                        Wqt, Wkt, Wvt, Wot, mask, rbuf);

  // Merged QKV: qk blocks [0,1024) + v blocks [1024,1536) in one launch
  gemm_qkv_k<<<dim3(1536), 512, 0, stream>>>(Xbf, Wqt, Wvt, bq, bk, bv,
                                             Qh, Kh, Vt);

  attn8_k<<<dim3(cH, cBS, 4), 256, 0, stream>>>(Qh, Kh, Vt, rbuf, Ob);

  // 8 XCD x 16 m-blocks x 4 n-blocks = 512 workgroups of 512
  gemm_bt3_k<<<dim3(512), 512, 0, stream>>>(Ob, Wot, bo, out);
}